// Round 1
// baseline (2027.554 us; speedup 1.0000x reference)
//
#include <hip/hip_runtime.h>
#include <math.h>

// Problem constants (from setup_inputs): B=4, S=1024, D=512, H=8
constexpr int B_ = 4, S_ = 1024, D_ = 512, H_ = 8;
constexpr float EPS_ = 1e-6f;
constexpr float MAXT = 1.0f - 1e-5f;

// ---------------- block reduction helpers (blockDim.x == 256) ----------------
__device__ __forceinline__ float blk_reduce_sum(float v, float* sm) {
    for (int o = 32; o > 0; o >>= 1) v += __shfl_down(v, o, 64);
    int lane = threadIdx.x & 63, wid = threadIdx.x >> 6;
    if (lane == 0) sm[wid] = v;
    __syncthreads();
    if (threadIdx.x == 0) {
        float r = sm[0] + sm[1] + sm[2] + sm[3];
        sm[0] = r;
    }
    __syncthreads();
    float r = sm[0];
    __syncthreads();
    return r;
}

__device__ __forceinline__ float blk_reduce_max(float v, float* sm) {
    for (int o = 32; o > 0; o >>= 1) v = fmaxf(v, __shfl_down(v, o, 64));
    int lane = threadIdx.x & 63, wid = threadIdx.x >> 6;
    if (lane == 0) sm[wid] = v;
    __syncthreads();
    if (threadIdx.x == 0) {
        float r = fmaxf(fmaxf(sm[0], sm[1]), fmaxf(sm[2], sm[3]));
        sm[0] = r;
    }
    __syncthreads();
    float r = sm[0];
    __syncthreads();
    return r;
}

// ---------------- logmap0 rows: t = atanh(min(n,M))/n * x, n=sqrt(max(ss,EPS)) ----------------
__global__ __launch_bounds__(256) void k_logmap_rows(const float* __restrict__ x,
                                                     float* __restrict__ t) {
    __shared__ float sm[8];
    int r = blockIdx.x;
    const float* xr = x + (size_t)r * D_;
    float* tr = t + (size_t)r * D_;
    float v0 = xr[threadIdx.x], v1 = xr[threadIdx.x + 256];
    float ss = blk_reduce_sum(v0 * v0 + v1 * v1, sm);
    float n = sqrtf(fmaxf(ss, EPS_));
    float f = atanhf(fminf(n, MAXT)) / n;
    tr[threadIdx.x] = f * v0;
    tr[threadIdx.x + 256] = f * v1;
}

// ---------------- expmap0 rows with modes ----------------
// mode 0: plain expmap (out = tanh(n)/n * y)
// mode 1: expmap + aux[row] = clip(ballnorm^2, <=1-1e-5)   (used for qn / kn)
// mode 2: v-mode: lam = 2/(1-vn); out = lam * ball; aux[row] = lam-1
__global__ __launch_bounds__(256) void k_expmap_rows(const float* __restrict__ y,
                                                     float* __restrict__ out,
                                                     float* __restrict__ aux, int mode) {
    __shared__ float sm[8];
    int r = blockIdx.x;
    const float* yr = y + (size_t)r * D_;
    float v0 = yr[threadIdx.x], v1 = yr[threadIdx.x + 256];
    float ss = blk_reduce_sum(v0 * v0 + v1 * v1, sm);
    float n = sqrtf(fmaxf(ss, EPS_));
    float f = tanhf(n) / n;
    float bn2 = fminf(f * f * ss, MAXT);  // clip(sum(x^2), 0, 1-1e-5)
    float scale = f;
    if (mode == 2) {
        float lam = 2.0f / (1.0f - bn2);
        scale = f * lam;
        if (threadIdx.x == 0) aux[r] = lam - 1.0f;
    } else if (mode == 1) {
        if (threadIdx.x == 0) aux[r] = bn2;
    }
    float* orow = out + (size_t)r * D_;
    orow[threadIdx.x] = scale * v0;
    orow[threadIdx.x + 256] = scale * v1;
}

// ---------------- generic 64x64x16 fp32 GEMM, NN layout ----------------
// C[orow,n] = sum_k A[m,k] * W[z][k,n] (+ bias[z][n]) (/ rowdiv[m] if DIV)
// orow = m unless Hz>1: m=(b,s) -> orow=(b*Hz+z)*S_+s  (head-remap for q-proj)
template <bool DIV>
__global__ __launch_bounds__(256) void k_gemm_nn(const float* __restrict__ A,
                                                 const float* __restrict__ W,
                                                 const float* __restrict__ bias,
                                                 float* __restrict__ C, int M, int N, int K,
                                                 int Hz, const float* __restrict__ rowdiv) {
    __shared__ float As[16][64];
    __shared__ float Bs[16][64];
    int m0 = blockIdx.y * 64, n0 = blockIdx.x * 64;
    int z = blockIdx.z;
    const float* Wz = W + (size_t)z * K * N;
    int tid = threadIdx.x;
    int am = tid >> 2, ak = (tid & 3) * 4;
    int bk = tid >> 4, bn = (tid & 15) * 4;
    int ty = tid >> 4, tx = tid & 15;
    float acc[4][4] = {};
    for (int k0 = 0; k0 < K; k0 += 16) {
        float4 av = *(const float4*)(A + (size_t)(m0 + am) * K + k0 + ak);
        As[ak + 0][am] = av.x; As[ak + 1][am] = av.y;
        As[ak + 2][am] = av.z; As[ak + 3][am] = av.w;
        float4 bv = *(const float4*)(Wz + (size_t)(k0 + bk) * N + n0 + bn);
        *(float4*)&Bs[bk][bn] = bv;
        __syncthreads();
#pragma unroll
        for (int kk = 0; kk < 16; kk++) {
            float a[4], b[4];
#pragma unroll
            for (int i = 0; i < 4; i++) a[i] = As[kk][ty * 4 + i];
#pragma unroll
            for (int j = 0; j < 4; j++) b[j] = Bs[kk][tx * 4 + j];
#pragma unroll
            for (int i = 0; i < 4; i++)
#pragma unroll
                for (int j = 0; j < 4; j++) acc[i][j] = fmaf(a[i], b[j], acc[i][j]);
        }
        __syncthreads();
    }
    for (int i = 0; i < 4; i++) {
        int m = m0 + ty * 4 + i;
        int orow = m;
        if (Hz > 1) { int b = m / S_, s = m % S_; orow = (b * Hz + z) * S_ + s; }
        float inv = 1.0f;
        if (DIV) inv = 1.0f / rowdiv[m];
        for (int j = 0; j < 4; j++) {
            int n = n0 + tx * 4 + j;
            float val = acc[i][j];
            if (bias) val += bias[(size_t)z * N + n];
            if (DIV) val *= inv;
            C[(size_t)orow * N + n] = val;
        }
    }
}

// ---------------- NT GEMM: C[m,n] = sum_k A[m,k]*Bm[n,k]  (scores = q @ k^T) ----------------
__global__ __launch_bounds__(256) void k_gemm_nt(const float* __restrict__ A,
                                                 const float* __restrict__ Bm,
                                                 float* __restrict__ C, int M, int N, int K) {
    __shared__ float As[16][64];
    __shared__ float Bs[16][64];
    int m0 = blockIdx.y * 64, n0 = blockIdx.x * 64;
    int tid = threadIdx.x;
    int am = tid >> 2, ak = (tid & 3) * 4;
    int ty = tid >> 4, tx = tid & 15;
    float acc[4][4] = {};
    for (int k0 = 0; k0 < K; k0 += 16) {
        float4 av = *(const float4*)(A + (size_t)(m0 + am) * K + k0 + ak);
        As[ak + 0][am] = av.x; As[ak + 1][am] = av.y;
        As[ak + 2][am] = av.z; As[ak + 3][am] = av.w;
        float4 bv = *(const float4*)(Bm + (size_t)(n0 + am) * K + k0 + ak);
        Bs[ak + 0][am] = bv.x; Bs[ak + 1][am] = bv.y;
        Bs[ak + 2][am] = bv.z; Bs[ak + 3][am] = bv.w;
        __syncthreads();
#pragma unroll
        for (int kk = 0; kk < 16; kk++) {
            float a[4], b[4];
#pragma unroll
            for (int i = 0; i < 4; i++) a[i] = As[kk][ty * 4 + i];
#pragma unroll
            for (int j = 0; j < 4; j++) b[j] = Bs[kk][tx * 4 + j];
#pragma unroll
            for (int i = 0; i < 4; i++)
#pragma unroll
                for (int j = 0; j < 4; j++) acc[i][j] = fmaf(a[i], b[j], acc[i][j]);
        }
        __syncthreads();
    }
    for (int i = 0; i < 4; i++) {
        int m = m0 + ty * 4 + i;
        for (int j = 0; j < 4; j++) C[(size_t)m * N + n0 + tx * 4 + j] = acc[i][j];
    }
}

// ---------------- final GEMM: yout[r,n] = sum_kk Ascale[urow]*U[urow,d]*Wo[kk,n] + bo[n] ----------------
// r=(b,s) over B*S rows; kk = h*512+d; urow = (b*H+h)*S+s
__global__ __launch_bounds__(256) void k_gemm_final(const float* __restrict__ U,
                                                    const float* __restrict__ Asc,
                                                    const float* __restrict__ Wo,
                                                    const float* __restrict__ bo,
                                                    float* __restrict__ Y) {
    __shared__ float As[16][64];
    __shared__ float Bs[16][64];
    const int N = D_, K = H_ * D_;
    int m0 = blockIdx.y * 64, n0 = blockIdx.x * 64;
    int tid = threadIdx.x;
    int am = tid >> 2, ak = (tid & 3) * 4;
    int bk = tid >> 4, bn = (tid & 15) * 4;
    int ty = tid >> 4, tx = tid & 15;
    float acc[4][4] = {};
    int r = m0 + am;
    int bb = r >> 10, s = r & 1023;
    for (int k0 = 0; k0 < K; k0 += 16) {
        int kk0 = k0 + ak;
        int h = kk0 >> 9, d = kk0 & 511;
        int urow = (bb * H_ + h) * S_ + s;
        float asc = Asc[urow];
        float4 av = *(const float4*)(U + (size_t)urow * D_ + d);
        As[ak + 0][am] = av.x * asc; As[ak + 1][am] = av.y * asc;
        As[ak + 2][am] = av.z * asc; As[ak + 3][am] = av.w * asc;
        float4 bv = *(const float4*)(Wo + (size_t)(k0 + bk) * N + n0 + bn);
        *(float4*)&Bs[bk][bn] = bv;
        __syncthreads();
#pragma unroll
        for (int kk = 0; kk < 16; kk++) {
            float a[4], b[4];
#pragma unroll
            for (int i = 0; i < 4; i++) a[i] = As[kk][ty * 4 + i];
#pragma unroll
            for (int j = 0; j < 4; j++) b[j] = Bs[kk][tx * 4 + j];
#pragma unroll
            for (int i = 0; i < 4; i++)
#pragma unroll
                for (int j = 0; j < 4; j++) acc[i][j] = fmaf(a[i], b[j], acc[i][j]);
        }
        __syncthreads();
    }
    for (int i = 0; i < 4; i++) {
        int m = m0 + ty * 4 + i;
        for (int j = 0; j < 4; j++) {
            int n = n0 + tx * 4 + j;
            Y[(size_t)m * N + n] = acc[i][j] + bo[n];
        }
    }
}

// ---------------- per-row sim -> exp(sim-max), den = sum E*(lam-1) ----------------
// Row r over H*S rows of one batch. Scores row holds dot(q,k); rewritten with E.
__global__ __launch_bounds__(256) void k_simexp(float* __restrict__ Srow,
                                                const float* __restrict__ qn_b,
                                                const float* __restrict__ kn_b,
                                                const float* __restrict__ lamM1_b,
                                                float* __restrict__ den_b,
                                                const float* __restrict__ stau,
                                                const float* __restrict__ sgam) {
    __shared__ float sm[8];
    int r = blockIdx.x;
    float itau = expf(stau[0]);   // 1/tau = exp(scale_tau)
    float gamma = sgam[0];
    float qn = qn_b[r];
    float omq = 1.0f - qn;
    float* row = Srow + (size_t)r * S_;
    float sim[4];
    float mx = -1e30f;
#pragma unroll
    for (int i = 0; i < 4; i++) {
        int kk = i * 256 + threadIdx.x;
        float dot = row[kk];
        float knv = kn_b[kk];
        float sq = fmaxf(qn + knv - 2.0f * dot, 0.0f);
        float dn = fmaxf(omq * (1.0f - knv), EPS_);
        float arg = fmaxf(1.0f + 2.0f * sq / dn, 1.0f + 1e-7f);
        float d = acoshf(arg);
        sim[i] = gamma - d * itau;
        mx = fmaxf(mx, sim[i]);
    }
    mx = blk_reduce_max(mx, sm);
    float lsum = 0.0f;
#pragma unroll
    for (int i = 0; i < 4; i++) {
        int kk = i * 256 + threadIdx.x;
        float e = expf(sim[i] - mx);
        row[kk] = e;
        lsum += e * lamM1_b[kk];
    }
    float den = blk_reduce_sum(lsum, sm);
    if (threadIdx.x == 0) den_b[r] = den;
}

// ---------------- per-(b,h,s): mobius 0.5-mul + logmap factors ----------------
__global__ __launch_bounds__(256) void k_headnorm(const float* __restrict__ U,
                                                  float* __restrict__ fac12,
                                                  float* __restrict__ tss) {
    __shared__ float sm[8];
    int r = blockIdx.x;
    const float* ur = U + (size_t)r * D_;
    float v0 = ur[threadIdx.x], v1 = ur[threadIdx.x + 256];
    float ss = blk_reduce_sum(v0 * v0 + v1 * v1, sm);
    if (threadIdx.x == 0) {
        float n = sqrtf(fmaxf(ss, EPS_));
        float a = 0.5f * atanhf(fminf(n, MAXT));
        float f1 = tanhf(a) / n;              // mid = f1 * u
        float mss = f1 * f1 * ss;             // |mid|^2
        float nm = sqrtf(fmaxf(mss, EPS_));
        float f2 = atanhf(fminf(nm, MAXT)) / nm;  // t_head = f2 * mid
        float f12 = f1 * f2;
        fac12[r] = f12;
        tss[r] = f12 * f12 * ss;              // |t_head|^2
    }
}

// ---------------- per-(b,s): concat expmap+logmap collapse -> Ascale ----------------
__global__ __launch_bounds__(256) void k_cat(const float* __restrict__ tss,
                                             const float* __restrict__ fac12,
                                             float* __restrict__ Asc) {
    int idx = blockIdx.x * blockDim.x + threadIdx.x;
    if (idx >= B_ * S_) return;
    int b = idx >> 10, s = idx & 1023;
    int base = b * H_ * S_ + s;
    float sum = 0.0f;
#pragma unroll
    for (int h = 0; h < H_; h++) sum += tss[base + h * S_];
    float nc = sqrtf(fmaxf(sum, EPS_));
    float f3 = tanhf(nc) / nc;                 // expmap0 of concat
    float css = f3 * f3 * sum;
    float nc2 = sqrtf(fmaxf(css, EPS_));
    float f4 = atanhf(fminf(nc2, MAXT)) / nc2; // logmap0 in final hlinear
    float g = f3 * f4;
#pragma unroll
    for (int h = 0; h < H_; h++) {
        int rr = base + h * S_;
        Asc[rr] = fac12[rr] * g;
    }
}

extern "C" void kernel_launch(void* const* d_in, const int* in_sizes, int n_in,
                              void* d_out, int out_size, void* d_ws, size_t ws_size,
                              hipStream_t stream) {
    (void)in_sizes; (void)n_in; (void)out_size; (void)ws_size;
    const float* query = (const float*)d_in[0];
    const float* key   = (const float*)d_in[1];
    const float* value = (const float*)d_in[2];
    const float* Wq = (const float*)d_in[3];
    const float* bq = (const float*)d_in[4];
    const float* Wk = (const float*)d_in[5];
    const float* bk = (const float*)d_in[6];
    const float* Wv = (const float*)d_in[7];
    const float* bv = (const float*)d_in[8];
    const float* Wo = (const float*)d_in[9];
    const float* bo = (const float*)d_in[10];
    const float* stau = (const float*)d_in[11];
    const float* sgam = (const float*)d_in[12];
    float* out = (float*)d_out;

    // workspace layout (floats)
    float* ws = (float*)d_ws;
    size_t o = 0;
    float* tq = ws + o; o += (size_t)B_ * S_ * D_;         // 2M
    float* tk = ws + o; o += (size_t)B_ * S_ * D_;
    float* tv = ws + o; o += (size_t)B_ * S_ * D_;
    float* yq = ws + o; o += (size_t)B_ * H_ * S_ * D_;    // 16M (yq -> qh -> u, aliased)
    float* yk = ws + o; o += (size_t)B_ * S_ * D_;         // yk -> k ball
    float* yv = ws + o; o += (size_t)B_ * S_ * D_;         // yv -> lam*v
    float* scores = ws + o; o += (size_t)H_ * S_ * S_;     // 8M, per-batch reuse
    float* yout = ws + o; o += (size_t)B_ * S_ * D_;
    float* kn    = ws + o; o += (size_t)B_ * S_;
    float* lamM1 = ws + o; o += (size_t)B_ * S_;
    float* qn    = ws + o; o += (size_t)B_ * H_ * S_;
    float* den   = ws + o; o += (size_t)B_ * H_ * S_;
    float* fac12 = ws + o; o += (size_t)B_ * H_ * S_;
    float* tss   = ws + o; o += (size_t)B_ * H_ * S_;
    float* Asc   = ws + o; o += (size_t)B_ * H_ * S_;

    // 1. tangent-space inputs
    k_logmap_rows<<<B_ * S_, 256, 0, stream>>>(query, tq);
    k_logmap_rows<<<B_ * S_, 256, 0, stream>>>(key, tk);
    k_logmap_rows<<<B_ * S_, 256, 0, stream>>>(value, tv);

    // 2. projections (linear part)
    k_gemm_nn<false><<<dim3(D_ / 64, B_ * S_ / 64, 1), 256, 0, stream>>>(
        tk, Wk, bk, yk, B_ * S_, D_, D_, 1, nullptr);
    k_gemm_nn<false><<<dim3(D_ / 64, B_ * S_ / 64, 1), 256, 0, stream>>>(
        tv, Wv, bv, yv, B_ * S_, D_, D_, 1, nullptr);
    k_gemm_nn<false><<<dim3(D_ / 64, B_ * S_ / 64, H_), 256, 0, stream>>>(
        tq, Wq, bq, yq, B_ * S_, D_, D_, H_, nullptr);

    // 3. expmap epilogues (+ aux stats)
    k_expmap_rows<<<B_ * S_, 256, 0, stream>>>(yk, yk, kn, 1);
    k_expmap_rows<<<B_ * S_, 256, 0, stream>>>(yv, yv, lamM1, 2);
    k_expmap_rows<<<B_ * H_ * S_, 256, 0, stream>>>(yq, yq, qn, 1);

    // 4. attention per batch (scores buffer reused)
    for (int b = 0; b < B_; b++) {
        const float* qh_b = yq + (size_t)b * H_ * S_ * D_;
        const float* k_b  = yk + (size_t)b * S_ * D_;
        const float* lv_b = yv + (size_t)b * S_ * D_;
        float* u_b = yq + (size_t)b * H_ * S_ * D_;  // alias: overwrite qh_b
        k_gemm_nt<<<dim3(S_ / 64, H_ * S_ / 64), 256, 0, stream>>>(
            qh_b, k_b, scores, H_ * S_, S_, D_);
        k_simexp<<<H_ * S_, 256, 0, stream>>>(
            scores, qn + (size_t)b * H_ * S_, kn + (size_t)b * S_,
            lamM1 + (size_t)b * S_, den + (size_t)b * H_ * S_, stau, sgam);
        k_gemm_nn<true><<<dim3(D_ / 64, H_ * S_ / 64, 1), 256, 0, stream>>>(
            scores, lv_b, nullptr, u_b, H_ * S_, D_, S_, 1, den + (size_t)b * H_ * S_);
    }

    // 5. mobius-half + logmap + concat factors
    k_headnorm<<<B_ * H_ * S_, 256, 0, stream>>>(yq, fac12, tss);
    k_cat<<<(B_ * S_ + 255) / 256, 256, 0, stream>>>(tss, fac12, Asc);

    // 6. output projection + final expmap
    k_gemm_final<<<dim3(D_ / 64, B_ * S_ / 64), 256, 0, stream>>>(yq, Asc, Wo, bo, yout);
    k_expmap_rows<<<B_ * S_, 256, 0, stream>>>(yout, out, nullptr, 0);
}

// Round 2
// 712.386 us; speedup vs baseline: 2.8461x; 2.8461x over previous
//
#include <hip/hip_runtime.h>
#include <math.h>

// Problem constants: B=4, S=1024, D=512, H=8
constexpr int B_ = 4, S_ = 1024, D_ = 512, H_ = 8;
constexpr float EPS_ = 1e-6f;
constexpr float MAXT = 1.0f - 1e-5f;

typedef __attribute__((ext_vector_type(8))) short bf16x8;
typedef __attribute__((ext_vector_type(4))) float f32x4;

__device__ __forceinline__ ushort f2b(float f) {
    unsigned u = __float_as_uint(f);
    unsigned r = u + 0x7fffu + ((u >> 16) & 1u);
    return (ushort)(r >> 16);
}
__device__ __forceinline__ float b2f(ushort h) {
    return __uint_as_float(((unsigned)h) << 16);
}

__device__ __forceinline__ void async16(const ushort* g, ushort* l) {
    __builtin_amdgcn_global_load_lds(
        (const __attribute__((address_space(1))) unsigned int*)g,
        (__attribute__((address_space(3))) unsigned int*)l, 16, 0, 0);
}

// ---------------- block reductions (blockDim.x == 256) ----------------
__device__ __forceinline__ float blk_reduce_sum(float v, float* sm) {
    for (int o = 32; o > 0; o >>= 1) v += __shfl_down(v, o, 64);
    int lane = threadIdx.x & 63, wid = threadIdx.x >> 6;
    if (lane == 0) sm[wid] = v;
    __syncthreads();
    if (threadIdx.x == 0) sm[0] = sm[0] + sm[1] + sm[2] + sm[3];
    __syncthreads();
    float r = sm[0];
    __syncthreads();
    return r;
}

// ---------------- MFMA NT-GEMM core: C(128x128) = A[128xK] * B[128xK]^T ----------------
// A,B bf16 row-major K-contiguous. LDS tiles As/Bs[128][32] bf16 with XOR chunk swizzle:
// slot s (16B) of row r holds logical k-chunk (s&3) ^ ((r>>1)&3).
__device__ __forceinline__ void gemm_core(const ushort* __restrict__ A,
                                          const ushort* __restrict__ B,
                                          int lda, int ldb, int K, int m0, int n0,
                                          ushort* As, ushort* Bs, f32x4 acc[4][4]) {
    const int tid = threadIdx.x;
    const int w = tid >> 6, lane = tid & 63;
    const int wm = w >> 1, wn = w & 1;
    const int quad = lane >> 4, lx = lane & 15;

    // staging: wave w stages rows [w*32, w*32+32) of both tiles, 16 rows per issue
    int r1 = w * 32 + (lane >> 2);
    int r2 = r1 + 16;
    int c = lane & 3;
    int q1 = c ^ ((r1 >> 1) & 3);
    int q2 = c ^ ((r2 >> 1) & 3);
    const ushort* a1 = A + (size_t)(m0 + r1) * lda + q1 * 8;
    const ushort* a2 = A + (size_t)(m0 + r2) * lda + q2 * 8;
    const ushort* b1 = B + (size_t)(n0 + r1) * ldb + q1 * 8;
    const ushort* b2 = B + (size_t)(n0 + r2) * ldb + q2 * 8;
    ushort* lA1 = As + (size_t)(w * 32) * 32;
    ushort* lA2 = As + (size_t)(w * 32 + 16) * 32;
    ushort* lB1 = Bs + (size_t)(w * 32) * 32;
    ushort* lB2 = Bs + (size_t)(w * 32 + 16) * 32;

    int raOff[4], rbOff[4];
#pragma unroll
    for (int i = 0; i < 4; i++) {
        int ra = wm * 64 + i * 16 + lx;
        raOff[i] = ra * 32 + (quad ^ ((ra >> 1) & 3)) * 8;
        int rb = wn * 64 + i * 16 + lx;
        rbOff[i] = rb * 32 + (quad ^ ((rb >> 1) & 3)) * 8;
    }
#pragma unroll
    for (int i = 0; i < 4; i++)
#pragma unroll
        for (int j = 0; j < 4; j++) acc[i][j] = (f32x4)(0.0f);

    for (int k0 = 0; k0 < K; k0 += 32) {
        __syncthreads();
        async16(a1 + k0, lA1);
        async16(a2 + k0, lA2);
        async16(b1 + k0, lB1);
        async16(b2 + k0, lB2);
        asm volatile("s_waitcnt vmcnt(0)" ::: "memory");
        __syncthreads();
        bf16x8 af[4], bfr[4];
#pragma unroll
        for (int i = 0; i < 4; i++) af[i] = *(const bf16x8*)(As + raOff[i]);
#pragma unroll
        for (int j = 0; j < 4; j++) bfr[j] = *(const bf16x8*)(Bs + rbOff[j]);
#pragma unroll
        for (int i = 0; i < 4; i++)
#pragma unroll
            for (int j = 0; j < 4; j++)
                acc[i][j] = __builtin_amdgcn_mfma_f32_16x16x32_bf16(af[i], bfr[j], acc[i][j], 0, 0, 0);
    }
}

// ---------------- projection / final GEMM: C fp32 = A*B^T + bias, optional head remap ----------------
__global__ __launch_bounds__(256) void k_gemm_proj(const ushort* __restrict__ A,
                                                   const ushort* __restrict__ BT,
                                                   const float* __restrict__ bias,
                                                   float* __restrict__ C, int K, int remap) {
    __shared__ ushort As[128 * 32], Bs[128 * 32];
    int z = blockIdx.z;
    const ushort* Bz = BT + (size_t)z * K * 512;
    const float* bz = bias + (size_t)z * 512;
    f32x4 acc[4][4];
    int m0 = blockIdx.y * 128, n0 = blockIdx.x * 128;
    gemm_core(A, Bz, K, K, K, m0, n0, As, Bs, acc);
    int tid = threadIdx.x, w = tid >> 6, lane = tid & 63;
    int wm = w >> 1, wn = w & 1, quad = lane >> 4, lx = lane & 15;
#pragma unroll
    for (int i = 0; i < 4; i++)
#pragma unroll
        for (int reg = 0; reg < 4; reg++) {
            int m = m0 + wm * 64 + i * 16 + quad * 4 + reg;
            size_t orow = remap ? (size_t)((m >> 10) * H_ + z) * S_ + (m & 1023) : (size_t)m;
#pragma unroll
            for (int j = 0; j < 4; j++) {
                int n = n0 + wn * 64 + j * 16 + lx;
                C[orow * 512 + n] = acc[i][j][reg] + bz[n];
            }
        }
}

// ---------------- score GEMM: dot -> poincare dist -> E=exp(-d*itau) bf16, den atomic ----------------
__global__ __launch_bounds__(256) void k_gemm_score(const ushort* __restrict__ Aq,
                                                    const ushort* __restrict__ Bk,
                                                    ushort* __restrict__ E,
                                                    float* __restrict__ den,
                                                    const float* __restrict__ qn,
                                                    const float* __restrict__ kn,
                                                    const float* __restrict__ lamM1,
                                                    const float* __restrict__ stau) {
    __shared__ ushort As[128 * 32], Bs[128 * 32];
    f32x4 acc[4][4];
    int m0 = blockIdx.y * 128, n0 = blockIdx.x * 128;
    gemm_core(Aq, Bk, 512, 512, 512, m0, n0, As, Bs, acc);
    float itau = expf(stau[0]);
    int tid = threadIdx.x, w = tid >> 6, lane = tid & 63;
    int wm = w >> 1, wn = w & 1, quad = lane >> 4, lx = lane & 15;
    float knv[4], lmv[4];
#pragma unroll
    for (int j = 0; j < 4; j++) {
        int n = n0 + wn * 64 + j * 16 + lx;
        knv[j] = kn[n];
        lmv[j] = lamM1[n];
    }
#pragma unroll
    for (int i = 0; i < 4; i++)
#pragma unroll
        for (int reg = 0; reg < 4; reg++) {
            int m = m0 + wm * 64 + i * 16 + quad * 4 + reg;
            float q = qn[m];
            float omq = 1.0f - q;
            float rsum = 0.0f;
#pragma unroll
            for (int j = 0; j < 4; j++) {
                float dot = acc[i][j][reg];
                float sq = fmaxf(q + knv[j] - 2.0f * dot, 0.0f);
                float dn = fmaxf(omq * (1.0f - knv[j]), EPS_);
                float arg = fmaxf(1.0f + 2.0f * sq / dn, 1.0f + 1e-7f);
                float d = acoshf(arg);
                float e = expf(-d * itau);
                ushort eb = f2b(e);
                int n = n0 + wn * 64 + j * 16 + lx;
                E[(size_t)m * 1024 + n] = eb;
                rsum += b2f(eb) * lmv[j];  // den consistent with rounded E
            }
            for (int o = 8; o; o >>= 1) rsum += __shfl_xor(rsum, o, 64);
            if (lx == 0) atomicAdd(&den[m], rsum);
        }
}

// ---------------- attn x V GEMM: U = (E * lamV^T) / den ----------------
__global__ __launch_bounds__(256) void k_gemm_attnv(const ushort* __restrict__ E,
                                                    const ushort* __restrict__ VT,
                                                    const float* __restrict__ den,
                                                    float* __restrict__ U) {
    __shared__ ushort As[128 * 32], Bs[128 * 32];
    f32x4 acc[4][4];
    int m0 = blockIdx.y * 128, n0 = blockIdx.x * 128;
    gemm_core(E, VT, 1024, 1024, 1024, m0, n0, As, Bs, acc);
    int tid = threadIdx.x, w = tid >> 6, lane = tid & 63;
    int wm = w >> 1, wn = w & 1, quad = lane >> 4, lx = lane & 15;
#pragma unroll
    for (int i = 0; i < 4; i++)
#pragma unroll
        for (int reg = 0; reg < 4; reg++) {
            int m = m0 + wm * 64 + i * 16 + quad * 4 + reg;
            float inv = 1.0f / fmaxf(den[m], EPS_);
#pragma unroll
            for (int j = 0; j < 4; j++) {
                int n = n0 + wn * 64 + j * 16 + lx;
                U[(size_t)m * 512 + n] = acc[i][j][reg] * inv;
            }
        }
}

// ---------------- logmap0 rows -> bf16 tangent ----------------
__global__ __launch_bounds__(256) void k_logmap_bf16(const float* __restrict__ x,
                                                     ushort* __restrict__ t) {
    __shared__ float sm[8];
    int r = blockIdx.x;
    const float* xr = x + (size_t)r * D_;
    float v0 = xr[threadIdx.x], v1 = xr[threadIdx.x + 256];
    float ss = blk_reduce_sum(v0 * v0 + v1 * v1, sm);
    float n = sqrtf(fmaxf(ss, EPS_));
    float f = atanhf(fminf(n, MAXT)) / n;
    ushort* tr = t + (size_t)r * D_;
    tr[threadIdx.x] = f2b(f * v0);
    tr[threadIdx.x + 256] = f2b(f * v1);
}

// ---------------- expmap rows with stats ----------------
// mode 0: fp32 out (final). mode 1: bf16 ball + aux=clip(|ball|^2). mode 2: lam*ball fp32 + aux=lam-1.
__global__ __launch_bounds__(256) void k_expmap_stats(const float* __restrict__ y,
                                                      float* __restrict__ outf,
                                                      ushort* __restrict__ outb,
                                                      float* __restrict__ aux, int mode) {
    __shared__ float sm[8];
    int r = blockIdx.x;
    const float* yr = y + (size_t)r * D_;
    float v0 = yr[threadIdx.x], v1 = yr[threadIdx.x + 256];
    float ss = blk_reduce_sum(v0 * v0 + v1 * v1, sm);
    float n = sqrtf(fmaxf(ss, EPS_));
    float f = tanhf(n) / n;
    if (mode == 0) {
        float* o = outf + (size_t)r * D_;
        o[threadIdx.x] = f * v0;
        o[threadIdx.x + 256] = f * v1;
        return;
    }
    ushort h0 = f2b(f * v0), h1 = f2b(f * v1);
    float x0 = b2f(h0), x1 = b2f(h1);
    float ss2 = blk_reduce_sum(x0 * x0 + x1 * x1, sm);
    float bn2 = fminf(ss2, MAXT);
    if (mode == 1) {
        ushort* o = outb + (size_t)r * D_;
        o[threadIdx.x] = h0;
        o[threadIdx.x + 256] = h1;
        if (threadIdx.x == 0) aux[r] = bn2;
    } else {
        float lam = 2.0f / (1.0f - bn2);
        float* o = outf + (size_t)r * D_;
        o[threadIdx.x] = lam * x0;
        o[threadIdx.x + 256] = lam * x1;
        if (threadIdx.x == 0) aux[r] = lam - 1.0f;
    }
}

// ---------------- transpose fp32 [R][C] -> bf16 [C][R] ----------------
__global__ __launch_bounds__(256) void k_transpose_f2b(const float* __restrict__ in,
                                                       ushort* __restrict__ out, int R, int C,
                                                       size_t zin, size_t zout) {
    __shared__ float t[32][33];
    in += (size_t)blockIdx.z * zin;
    out += (size_t)blockIdx.z * zout;
    int c0 = blockIdx.x * 32, r0 = blockIdx.y * 32;
    int tx = threadIdx.x & 31, ty = threadIdx.x >> 5;
    for (int rr = ty; rr < 32; rr += 8) t[rr][tx] = in[(size_t)(r0 + rr) * C + c0 + tx];
    __syncthreads();
    for (int rr = ty; rr < 32; rr += 8)
        out[(size_t)(c0 + rr) * R + r0 + tx] = f2b(t[tx][rr]);
}

// ---------------- per-(b,h,s): mobius 0.5-mul + logmap factors ----------------
__global__ __launch_bounds__(256) void k_headnorm(const float* __restrict__ U,
                                                  float* __restrict__ fac12,
                                                  float* __restrict__ tss) {
    __shared__ float sm[8];
    int r = blockIdx.x;
    const float* ur = U + (size_t)r * D_;
    float v0 = ur[threadIdx.x], v1 = ur[threadIdx.x + 256];
    float ss = blk_reduce_sum(v0 * v0 + v1 * v1, sm);
    if (threadIdx.x == 0) {
        float n = sqrtf(fmaxf(ss, EPS_));
        float a = 0.5f * atanhf(fminf(n, MAXT));
        float f1 = tanhf(a) / n;
        float mss = f1 * f1 * ss;
        float nm = sqrtf(fmaxf(mss, EPS_));
        float f2 = atanhf(fminf(nm, MAXT)) / nm;
        float f12 = f1 * f2;
        fac12[r] = f12;
        tss[r] = f12 * f12 * ss;
    }
}

// ---------------- per-(b,s): concat expmap+logmap collapse -> Ascale ----------------
__global__ __launch_bounds__(256) void k_cat(const float* __restrict__ tss,
                                             const float* __restrict__ fac12,
                                             float* __restrict__ Asc) {
    int idx = blockIdx.x * blockDim.x + threadIdx.x;
    if (idx >= B_ * S_) return;
    int b = idx >> 10, s = idx & 1023;
    int base = b * H_ * S_ + s;
    float sum = 0.0f;
#pragma unroll
    for (int h = 0; h < H_; h++) sum += tss[base + h * S_];
    float nc = sqrtf(fmaxf(sum, EPS_));
    float f3 = tanhf(nc) / nc;
    float css = f3 * f3 * sum;
    float nc2 = sqrtf(fmaxf(css, EPS_));
    float f4 = atanhf(fminf(nc2, MAXT)) / nc2;
    float g = f3 * f4;
#pragma unroll
    for (int h = 0; h < H_; h++) {
        int rr = base + h * S_;
        Asc[rr] = fac12[rr] * g;
    }
}

// ---------------- build concat-A bf16: Acat[(b,s), h*512+d] = Asc*U ----------------
__global__ __launch_bounds__(256) void k_scale_cat(const float* __restrict__ U,
                                                   const float* __restrict__ Asc,
                                                   ushort* __restrict__ Acat) {
    int idx = blockIdx.x * 256 + threadIdx.x;
    int d = idx & 511, h = (idx >> 9) & 7, s = (idx >> 12) & 1023, bb = idx >> 22;
    int urow = (bb * H_ + h) * S_ + s;
    Acat[idx] = f2b(Asc[urow] * U[(size_t)urow * 512 + d]);
}

extern "C" void kernel_launch(void* const* d_in, const int* in_sizes, int n_in,
                              void* d_out, int out_size, void* d_ws, size_t ws_size,
                              hipStream_t stream) {
    (void)in_sizes; (void)n_in; (void)out_size; (void)ws_size;
    const float* query = (const float*)d_in[0];
    const float* key = (const float*)d_in[1];
    const float* value = (const float*)d_in[2];
    const float* Wq = (const float*)d_in[3];
    const float* bq = (const float*)d_in[4];
    const float* Wk = (const float*)d_in[5];
    const float* bk = (const float*)d_in[6];
    const float* Wv = (const float*)d_in[7];
    const float* bv = (const float*)d_in[8];
    const float* Wo = (const float*)d_in[9];
    const float* bo = (const float*)d_in[10];
    const float* stau = (const float*)d_in[11];
    float* out = (float*)d_out;

    char* p = (char*)d_ws;
    auto alloc = [&](size_t bytes) {
        char* r = p;
        p += (bytes + 255) & ~(size_t)255;
        return r;
    };
    ushort* tq = (ushort*)alloc((size_t)4096 * 512 * 2);
    ushort* tk = (ushort*)alloc((size_t)4096 * 512 * 2);
    ushort* tv = (ushort*)alloc((size_t)4096 * 512 * 2);
    ushort* WqT = (ushort*)alloc((size_t)8 * 512 * 512 * 2);
    ushort* WkT = (ushort*)alloc((size_t)512 * 512 * 2);
    ushort* WvT = (ushort*)alloc((size_t)512 * 512 * 2);
    ushort* WoT = (ushort*)alloc((size_t)4096 * 512 * 2);
    float* yq = (float*)alloc((size_t)32768 * 512 * 4);  // also U after attnv
    float* yk = (float*)alloc((size_t)4096 * 512 * 4);
    float* yv = (float*)alloc((size_t)4096 * 512 * 4);
    ushort* qh = (ushort*)alloc((size_t)32768 * 512 * 2);
    ushort* kball = (ushort*)alloc((size_t)4096 * 512 * 2);
    float* lamv = (float*)alloc((size_t)4096 * 512 * 4);
    ushort* lamvT = (ushort*)alloc((size_t)4 * 512 * 1024 * 2);
    ushort* Sc = (ushort*)alloc((size_t)8192 * 1024 * 2);
    ushort* Acat = (ushort*)alloc((size_t)4096 * 4096 * 2);
    float* yout = (float*)alloc((size_t)4096 * 512 * 4);
    float* kn = (float*)alloc(4096 * 4);
    float* lamM1 = (float*)alloc(4096 * 4);
    float* qn = (float*)alloc(32768 * 4);
    float* den = (float*)alloc(32768 * 4);
    float* fac12 = (float*)alloc(32768 * 4);
    float* tss = (float*)alloc(32768 * 4);
    float* Asc = (float*)alloc(32768 * 4);

    hipMemsetAsync(den, 0, 32768 * 4, stream);

    // 1. tangent inputs (bf16)
    k_logmap_bf16<<<4096, 256, 0, stream>>>(query, tq);
    k_logmap_bf16<<<4096, 256, 0, stream>>>(key, tk);
    k_logmap_bf16<<<4096, 256, 0, stream>>>(value, tv);

    // 2. weight transposes -> bf16 [N][K]
    k_transpose_f2b<<<dim3(16, 16, 1), 256, 0, stream>>>(Wk, WkT, 512, 512, 0, 0);
    k_transpose_f2b<<<dim3(16, 16, 1), 256, 0, stream>>>(Wv, WvT, 512, 512, 0, 0);
    k_transpose_f2b<<<dim3(16, 16, 8), 256, 0, stream>>>(Wq, WqT, 512, 512, (size_t)512 * 512,
                                                         (size_t)512 * 512);
    k_transpose_f2b<<<dim3(16, 128, 1), 256, 0, stream>>>(Wo, WoT, 4096, 512, 0, 0);

    // 3. projections (MFMA)
    k_gemm_proj<<<dim3(4, 32, 1), 256, 0, stream>>>(tk, WkT, bk, yk, 512, 0);
    k_gemm_proj<<<dim3(4, 32, 1), 256, 0, stream>>>(tv, WvT, bv, yv, 512, 0);
    k_gemm_proj<<<dim3(4, 32, 8), 256, 0, stream>>>(tq, WqT, bq, yq, 512, 1);

    // 4. expmap epilogues + stats
    k_expmap_stats<<<4096, 256, 0, stream>>>(yk, nullptr, kball, kn, 1);
    k_expmap_stats<<<4096, 256, 0, stream>>>(yv, lamv, nullptr, lamM1, 2);
    k_expmap_stats<<<32768, 256, 0, stream>>>(yq, nullptr, qh, qn, 1);
    k_transpose_f2b<<<dim3(16, 32, 4), 256, 0, stream>>>(lamv, lamvT, 1024, 512,
                                                         (size_t)1024 * 512, (size_t)512 * 1024);

    // 5. attention per batch
    for (int b = 0; b < B_; b++) {
        k_gemm_score<<<dim3(8, 64), 256, 0, stream>>>(
            qh + (size_t)b * 8192 * 512, kball + (size_t)b * 1024 * 512, Sc, den + b * 8192,
            qn + b * 8192, kn + b * 1024, lamM1 + b * 1024, stau);
        k_gemm_attnv<<<dim3(4, 64), 256, 0, stream>>>(
            Sc, lamvT + (size_t)b * 512 * 1024, den + b * 8192, yq + (size_t)b * 8192 * 512);
    }

    // 6. head post-processing
    k_headnorm<<<32768, 256, 0, stream>>>(yq, fac12, tss);
    k_cat<<<16, 256, 0, stream>>>(tss, fac12, Asc);
    k_scale_cat<<<65536, 256, 0, stream>>>(yq, Asc, Acat);

    // 7. output projection + final expmap
    k_gemm_proj<<<dim3(4, 32, 1), 256, 0, stream>>>(Acat, WoT, bo, yout, 4096, 0);
    k_expmap_stats<<<4096, 256, 0, stream>>>(yout, out, nullptr, nullptr, 0);
}

// Round 3
// 564.797 us; speedup vs baseline: 3.5899x; 1.2613x over previous
//
#include <hip/hip_runtime.h>
#include <math.h>

// Problem constants: B=4, S=1024, D=512, H=8
constexpr int B_ = 4, S_ = 1024, D_ = 512, H_ = 8;
constexpr float EPS_ = 1e-6f;
constexpr float MAXT = 1.0f - 1e-5f;

typedef __attribute__((ext_vector_type(8))) short bf16x8;
typedef __attribute__((ext_vector_type(4))) float f32x4;

__device__ __forceinline__ ushort f2b(float f) {
    unsigned u = __float_as_uint(f);
    unsigned r = u + 0x7fffu + ((u >> 16) & 1u);
    return (ushort)(r >> 16);
}
__device__ __forceinline__ float b2f(ushort h) {
    return __uint_as_float(((unsigned)h) << 16);
}

__device__ __forceinline__ void async16(const ushort* g, ushort* l) {
    __builtin_amdgcn_global_load_lds(
        (const __attribute__((address_space(1))) unsigned int*)g,
        (__attribute__((address_space(3))) unsigned int*)l, 16, 0, 0);
}

// ---------------- block reductions (blockDim.x == 256) ----------------
__device__ __forceinline__ float blk_reduce_sum(float v, float* sm) {
    for (int o = 32; o > 0; o >>= 1) v += __shfl_down(v, o, 64);
    int lane = threadIdx.x & 63, wid = threadIdx.x >> 6;
    if (lane == 0) sm[wid] = v;
    __syncthreads();
    if (threadIdx.x == 0) sm[0] = sm[0] + sm[1] + sm[2] + sm[3];
    __syncthreads();
    float r = sm[0];
    __syncthreads();
    return r;
}

// ---------------- MFMA NT-GEMM core: C(128x128) = A[128xK] * B[128xK]^T ----------------
// A,B bf16 row-major K-contiguous. LDS tiles As/Bs[128][32] bf16 with XOR chunk swizzle.
__device__ __forceinline__ void gemm_core(const ushort* __restrict__ A,
                                          const ushort* __restrict__ B,
                                          int lda, int ldb, int K, int m0, int n0,
                                          ushort* As, ushort* Bs, f32x4 acc[4][4]) {
    const int tid = threadIdx.x;
    const int w = tid >> 6, lane = tid & 63;
    const int wm = w >> 1, wn = w & 1;
    const int quad = lane >> 4, lx = lane & 15;

    int r1 = w * 32 + (lane >> 2);
    int r2 = r1 + 16;
    int c = lane & 3;
    int q1 = c ^ ((r1 >> 1) & 3);
    int q2 = c ^ ((r2 >> 1) & 3);
    const ushort* a1 = A + (size_t)(m0 + r1) * lda + q1 * 8;
    const ushort* a2 = A + (size_t)(m0 + r2) * lda + q2 * 8;
    const ushort* b1 = B + (size_t)(n0 + r1) * ldb + q1 * 8;
    const ushort* b2 = B + (size_t)(n0 + r2) * ldb + q2 * 8;
    ushort* lA1 = As + (size_t)(w * 32) * 32;
    ushort* lA2 = As + (size_t)(w * 32 + 16) * 32;
    ushort* lB1 = Bs + (size_t)(w * 32) * 32;
    ushort* lB2 = Bs + (size_t)(w * 32 + 16) * 32;

    int raOff[4], rbOff[4];
#pragma unroll
    for (int i = 0; i < 4; i++) {
        int ra = wm * 64 + i * 16 + lx;
        raOff[i] = ra * 32 + (quad ^ ((ra >> 1) & 3)) * 8;
        int rb = wn * 64 + i * 16 + lx;
        rbOff[i] = rb * 32 + (quad ^ ((rb >> 1) & 3)) * 8;
    }
#pragma unroll
    for (int i = 0; i < 4; i++)
#pragma unroll
        for (int j = 0; j < 4; j++) acc[i][j] = (f32x4)(0.0f);

    for (int k0 = 0; k0 < K; k0 += 32) {
        __syncthreads();
        async16(a1 + k0, lA1);
        async16(a2 + k0, lA2);
        async16(b1 + k0, lB1);
        async16(b2 + k0, lB2);
        asm volatile("s_waitcnt vmcnt(0)" ::: "memory");
        __syncthreads();
        bf16x8 af[4], bfr[4];
#pragma unroll
        for (int i = 0; i < 4; i++) af[i] = *(const bf16x8*)(As + raOff[i]);
#pragma unroll
        for (int j = 0; j < 4; j++) bfr[j] = *(const bf16x8*)(Bs + rbOff[j]);
#pragma unroll
        for (int i = 0; i < 4; i++)
#pragma unroll
            for (int j = 0; j < 4; j++)
                acc[i][j] = __builtin_amdgcn_mfma_f32_16x16x32_bf16(af[i], bfr[j], acc[i][j], 0, 0, 0);
    }
}

// ---------------- fused q/k/v projection: z=0 -> K proj, z=1 -> V proj, z>=2 -> Q head z-2 ----------------
__global__ __launch_bounds__(256) void k_gemm_proj_all(const ushort* __restrict__ tq,
                                                       const ushort* __restrict__ tk,
                                                       const ushort* __restrict__ tv,
                                                       const ushort* __restrict__ WqT,
                                                       const ushort* __restrict__ WkT,
                                                       const ushort* __restrict__ WvT,
                                                       const float* __restrict__ bq,
                                                       const float* __restrict__ bk,
                                                       const float* __restrict__ bv,
                                                       float* __restrict__ yq,
                                                       float* __restrict__ yk,
                                                       float* __restrict__ yv) {
    __shared__ ushort As[128 * 32], Bs[128 * 32];
    int z = blockIdx.z;
    const ushort* A;
    const ushort* BT;
    const float* bias;
    float* C;
    int remap = 0, h = 0;
    if (z == 0) { A = tk; BT = WkT; bias = bk; C = yk; }
    else if (z == 1) { A = tv; BT = WvT; bias = bv; C = yv; }
    else {
        h = z - 2;
        A = tq; BT = WqT + (size_t)h * 512 * 512; bias = bq + (size_t)h * 512;
        C = yq; remap = 1;
    }
    f32x4 acc[4][4];
    int m0 = blockIdx.y * 128, n0 = blockIdx.x * 128;
    gemm_core(A, BT, 512, 512, 512, m0, n0, As, Bs, acc);
    int tid = threadIdx.x, w = tid >> 6, lane = tid & 63;
    int wm = w >> 1, wn = w & 1, quad = lane >> 4, lx = lane & 15;
#pragma unroll
    for (int i = 0; i < 4; i++)
#pragma unroll
        for (int reg = 0; reg < 4; reg++) {
            int m = m0 + wm * 64 + i * 16 + quad * 4 + reg;
            size_t orow = remap ? (size_t)((m >> 10) * H_ + h) * S_ + (m & 1023) : (size_t)m;
#pragma unroll
            for (int j = 0; j < 4; j++) {
                int n = n0 + wn * 64 + j * 16 + lx;
                C[orow * 512 + n] = acc[i][j][reg] + bias[n];
            }
        }
}

// ---------------- score GEMM (batched over z): dist -> E bf16, den atomic ----------------
__global__ __launch_bounds__(256) void k_gemm_score(const ushort* __restrict__ Aq,
                                                    const ushort* __restrict__ Bk,
                                                    ushort* __restrict__ E,
                                                    float* __restrict__ den,
                                                    const float* __restrict__ qn,
                                                    const float* __restrict__ kn,
                                                    const float* __restrict__ lamM1,
                                                    const float* __restrict__ stau) {
    __shared__ ushort As[128 * 32], Bs[128 * 32];
    int b = blockIdx.z;
    Aq += (size_t)b * 8192 * 512;
    Bk += (size_t)b * 1024 * 512;
    E += (size_t)b * 8192 * 1024;
    den += (size_t)b * 8192;
    qn += (size_t)b * 8192;
    kn += (size_t)b * 1024;
    lamM1 += (size_t)b * 1024;
    f32x4 acc[4][4];
    int m0 = blockIdx.y * 128, n0 = blockIdx.x * 128;
    gemm_core(Aq, Bk, 512, 512, 512, m0, n0, As, Bs, acc);
    float itau = expf(stau[0]);
    int tid = threadIdx.x, w = tid >> 6, lane = tid & 63;
    int wm = w >> 1, wn = w & 1, quad = lane >> 4, lx = lane & 15;
    float knv[4], lmv[4];
#pragma unroll
    for (int j = 0; j < 4; j++) {
        int n = n0 + wn * 64 + j * 16 + lx;
        knv[j] = kn[n];
        lmv[j] = lamM1[n];
    }
#pragma unroll
    for (int i = 0; i < 4; i++)
#pragma unroll
        for (int reg = 0; reg < 4; reg++) {
            int m = m0 + wm * 64 + i * 16 + quad * 4 + reg;
            float q = qn[m];
            float omq = 1.0f - q;
            float rsum = 0.0f;
#pragma unroll
            for (int j = 0; j < 4; j++) {
                float dot = acc[i][j][reg];
                float sq = fmaxf(q + knv[j] - 2.0f * dot, 0.0f);
                float dn = fmaxf(omq * (1.0f - knv[j]), EPS_);
                float arg = fmaxf(1.0f + 2.0f * sq / dn, 1.0f + 1e-7f);
                float d = acoshf(arg);
                float e = expf(-d * itau);
                ushort eb = f2b(e);
                int n = n0 + wn * 64 + j * 16 + lx;
                E[(size_t)m * 1024 + n] = eb;
                rsum += b2f(eb) * lmv[j];
            }
            for (int o = 8; o; o >>= 1) rsum += __shfl_xor(rsum, o, 64);
            if (lx == 0) atomicAdd(&den[m], rsum);
        }
}

// ---------------- attn x V GEMM (batched over z): U = (E * lamV^T) / den ----------------
__global__ __launch_bounds__(256) void k_gemm_attnv(const ushort* __restrict__ E,
                                                    const ushort* __restrict__ VT,
                                                    const float* __restrict__ den,
                                                    float* __restrict__ U) {
    __shared__ ushort As[128 * 32], Bs[128 * 32];
    int b = blockIdx.z;
    E += (size_t)b * 8192 * 1024;
    VT += (size_t)b * 512 * 1024;
    den += (size_t)b * 8192;
    U += (size_t)b * 8192 * 512;
    f32x4 acc[4][4];
    int m0 = blockIdx.y * 128, n0 = blockIdx.x * 128;
    gemm_core(E, VT, 1024, 1024, 1024, m0, n0, As, Bs, acc);
    int tid = threadIdx.x, w = tid >> 6, lane = tid & 63;
    int wm = w >> 1, wn = w & 1, quad = lane >> 4, lx = lane & 15;
#pragma unroll
    for (int i = 0; i < 4; i++)
#pragma unroll
        for (int reg = 0; reg < 4; reg++) {
            int m = m0 + wm * 64 + i * 16 + quad * 4 + reg;
            float inv = 1.0f / fmaxf(den[m], EPS_);
#pragma unroll
            for (int j = 0; j < 4; j++) {
                int n = n0 + wn * 64 + j * 16 + lx;
                U[(size_t)m * 512 + n] = acc[i][j][reg] * inv;
            }
        }
}

// ---------------- final GEMM split-K: partial[z] = Acat[:, z*1024:(z+1)*1024] * WoT_chunk^T ----------------
__global__ __launch_bounds__(256) void k_gemm_sk(const ushort* __restrict__ Acat,
                                                 const ushort* __restrict__ WoT,
                                                 float* __restrict__ Cp) {
    __shared__ ushort As[128 * 32], Bs[128 * 32];
    int z = blockIdx.z;
    const ushort* A = Acat + (size_t)z * 1024;
    const ushort* BT = WoT + (size_t)z * 1024;
    float* C = Cp + (size_t)z * 4096 * 512;
    f32x4 acc[4][4];
    int m0 = blockIdx.y * 128, n0 = blockIdx.x * 128;
    gemm_core(A, BT, 4096, 4096, 1024, m0, n0, As, Bs, acc);
    int tid = threadIdx.x, w = tid >> 6, lane = tid & 63;
    int wm = w >> 1, wn = w & 1, quad = lane >> 4, lx = lane & 15;
#pragma unroll
    for (int i = 0; i < 4; i++)
#pragma unroll
        for (int reg = 0; reg < 4; reg++) {
            int m = m0 + wm * 64 + i * 16 + quad * 4 + reg;
#pragma unroll
            for (int j = 0; j < 4; j++) {
                int n = n0 + wn * 64 + j * 16 + lx;
                C[(size_t)m * 512 + n] = acc[i][j][reg];
            }
        }
}

// ---------------- final reduce (4 partials + bias) + expmap0 -> out ----------------
__global__ __launch_bounds__(256) void k_final_reduce_expmap(const float* __restrict__ Cp,
                                                             const float* __restrict__ bo,
                                                             float* __restrict__ out) {
    __shared__ float sm[8];
    int r = blockIdx.x;
    float v0 = bo[threadIdx.x], v1 = bo[threadIdx.x + 256];
#pragma unroll
    for (int z = 0; z < 4; z++) {
        const float* row = Cp + ((size_t)z * 4096 + r) * 512;
        v0 += row[threadIdx.x];
        v1 += row[threadIdx.x + 256];
    }
    float ss = blk_reduce_sum(v0 * v0 + v1 * v1, sm);
    float n = sqrtf(fmaxf(ss, EPS_));
    float f = tanhf(n) / n;
    float* o = out + (size_t)r * D_;
    o[threadIdx.x] = f * v0;
    o[threadIdx.x + 256] = f * v1;
}

// ---------------- logmap0 rows -> bf16 tangent (y selects q/k/v) ----------------
__global__ __launch_bounds__(256) void k_logmap_bf16(const float* __restrict__ q,
                                                     const float* __restrict__ k,
                                                     const float* __restrict__ v,
                                                     ushort* __restrict__ tq,
                                                     ushort* __restrict__ tk,
                                                     ushort* __restrict__ tv) {
    __shared__ float sm[8];
    const float* x = (blockIdx.y == 0) ? q : (blockIdx.y == 1) ? k : v;
    ushort* t = (blockIdx.y == 0) ? tq : (blockIdx.y == 1) ? tk : tv;
    int r = blockIdx.x;
    const float* xr = x + (size_t)r * D_;
    float v0 = xr[threadIdx.x], v1 = xr[threadIdx.x + 256];
    float ss = blk_reduce_sum(v0 * v0 + v1 * v1, sm);
    float n = sqrtf(fmaxf(ss, EPS_));
    float f = atanhf(fminf(n, MAXT)) / n;
    ushort* tr = t + (size_t)r * D_;
    tr[threadIdx.x] = f2b(f * v0);
    tr[threadIdx.x + 256] = f2b(f * v1);
}

// ---------------- expmap rows with stats ----------------
// mode 1: bf16 ball + aux=clip(|ball|^2). mode 2: lam*ball fp32 + aux=lam-1.
__global__ __launch_bounds__(256) void k_expmap_stats(const float* __restrict__ y,
                                                      float* __restrict__ outf,
                                                      ushort* __restrict__ outb,
                                                      float* __restrict__ aux, int mode) {
    __shared__ float sm[8];
    int r = blockIdx.x;
    const float* yr = y + (size_t)r * D_;
    float v0 = yr[threadIdx.x], v1 = yr[threadIdx.x + 256];
    float ss = blk_reduce_sum(v0 * v0 + v1 * v1, sm);
    float n = sqrtf(fmaxf(ss, EPS_));
    float f = tanhf(n) / n;
    ushort h0 = f2b(f * v0), h1 = f2b(f * v1);
    float x0 = b2f(h0), x1 = b2f(h1);
    float ss2 = blk_reduce_sum(x0 * x0 + x1 * x1, sm);
    float bn2 = fminf(ss2, MAXT);
    if (mode == 1) {
        ushort* o = outb + (size_t)r * D_;
        o[threadIdx.x] = h0;
        o[threadIdx.x + 256] = h1;
        if (threadIdx.x == 0) aux[r] = bn2;
    } else {
        float lam = 2.0f / (1.0f - bn2);
        float* o = outf + (size_t)r * D_;
        o[threadIdx.x] = lam * x0;
        o[threadIdx.x + 256] = lam * x1;
        if (threadIdx.x == 0) aux[r] = lam - 1.0f;
    }
}

// ---------------- transpose fp32 [R][C] -> bf16 [C][R] ----------------
__global__ __launch_bounds__(256) void k_transpose_f2b(const float* __restrict__ in,
                                                       ushort* __restrict__ out, int R, int C,
                                                       size_t zin, size_t zout) {
    __shared__ float t[32][33];
    in += (size_t)blockIdx.z * zin;
    out += (size_t)blockIdx.z * zout;
    int c0 = blockIdx.x * 32, r0 = blockIdx.y * 32;
    int tx = threadIdx.x & 31, ty = threadIdx.x >> 5;
    for (int rr = ty; rr < 32; rr += 8) t[rr][tx] = in[(size_t)(r0 + rr) * C + c0 + tx];
    __syncthreads();
    for (int rr = ty; rr < 32; rr += 8)
        out[(size_t)(c0 + rr) * R + r0 + tx] = f2b(t[tx][rr]);
}

// ---------------- per-(b,h,s): mobius 0.5-mul + logmap factors ----------------
__global__ __launch_bounds__(256) void k_headnorm(const float* __restrict__ U,
                                                  float* __restrict__ fac12,
                                                  float* __restrict__ tss) {
    __shared__ float sm[8];
    int r = blockIdx.x;
    const float* ur = U + (size_t)r * D_;
    float v0 = ur[threadIdx.x], v1 = ur[threadIdx.x + 256];
    float ss = blk_reduce_sum(v0 * v0 + v1 * v1, sm);
    if (threadIdx.x == 0) {
        float n = sqrtf(fmaxf(ss, EPS_));
        float a = 0.5f * atanhf(fminf(n, MAXT));
        float f1 = tanhf(a) / n;
        float mss = f1 * f1 * ss;
        float nm = sqrtf(fmaxf(mss, EPS_));
        float f2 = atanhf(fminf(nm, MAXT)) / nm;
        float f12 = f1 * f2;
        fac12[r] = f12;
        tss[r] = f12 * f12 * ss;
    }
}

// ---------------- per-(b,s): concat expmap+logmap collapse -> Ascale ----------------
__global__ __launch_bounds__(256) void k_cat(const float* __restrict__ tss,
                                             const float* __restrict__ fac12,
                                             float* __restrict__ Asc) {
    int idx = blockIdx.x * blockDim.x + threadIdx.x;
    if (idx >= B_ * S_) return;
    int b = idx >> 10, s = idx & 1023;
    int base = b * H_ * S_ + s;
    float sum = 0.0f;
#pragma unroll
    for (int h = 0; h < H_; h++) sum += tss[base + h * S_];
    float nc = sqrtf(fmaxf(sum, EPS_));
    float f3 = tanhf(nc) / nc;
    float css = f3 * f3 * sum;
    float nc2 = sqrtf(fmaxf(css, EPS_));
    float f4 = atanhf(fminf(nc2, MAXT)) / nc2;
    float g = f3 * f4;
#pragma unroll
    for (int h = 0; h < H_; h++) {
        int rr = base + h * S_;
        Asc[rr] = fac12[rr] * g;
    }
}

// ---------------- build concat-A bf16: Acat[(b,s), h*512+d] = Asc*U ----------------
__global__ __launch_bounds__(256) void k_scale_cat(const float* __restrict__ U,
                                                   const float* __restrict__ Asc,
                                                   ushort* __restrict__ Acat) {
    int idx = blockIdx.x * 256 + threadIdx.x;
    int d = idx & 511, h = (idx >> 9) & 7, s = (idx >> 12) & 1023, bb = idx >> 22;
    int urow = (bb * H_ + h) * S_ + s;
    Acat[idx] = f2b(Asc[urow] * U[(size_t)urow * 512 + d]);
}

extern "C" void kernel_launch(void* const* d_in, const int* in_sizes, int n_in,
                              void* d_out, int out_size, void* d_ws, size_t ws_size,
                              hipStream_t stream) {
    (void)in_sizes; (void)n_in; (void)out_size; (void)ws_size;
    const float* query = (const float*)d_in[0];
    const float* key = (const float*)d_in[1];
    const float* value = (const float*)d_in[2];
    const float* Wq = (const float*)d_in[3];
    const float* bq = (const float*)d_in[4];
    const float* Wk = (const float*)d_in[5];
    const float* bk = (const float*)d_in[6];
    const float* Wv = (const float*)d_in[7];
    const float* bv = (const float*)d_in[8];
    const float* Wo = (const float*)d_in[9];
    const float* bo = (const float*)d_in[10];
    const float* stau = (const float*)d_in[11];
    float* out = (float*)d_out;

    char* p = (char*)d_ws;
    auto alloc = [&](size_t bytes) {
        char* r = p;
        p += (bytes + 255) & ~(size_t)255;
        return r;
    };
    ushort* tq = (ushort*)alloc((size_t)4096 * 512 * 2);
    ushort* tk = (ushort*)alloc((size_t)4096 * 512 * 2);
    ushort* tv = (ushort*)alloc((size_t)4096 * 512 * 2);
    ushort* WqT = (ushort*)alloc((size_t)8 * 512 * 512 * 2);
    ushort* WkT = (ushort*)alloc((size_t)512 * 512 * 2);
    ushort* WvT = (ushort*)alloc((size_t)512 * 512 * 2);
    ushort* WoT = (ushort*)alloc((size_t)4096 * 512 * 2);
    float* yq = (float*)alloc((size_t)32768 * 512 * 4);  // also U after attnv
    float* yk = (float*)alloc((size_t)4096 * 512 * 4);
    float* yv = (float*)alloc((size_t)4096 * 512 * 4);
    ushort* qh = (ushort*)alloc((size_t)32768 * 512 * 2);  // aliased: Cp partials after scores
    ushort* kball = (ushort*)alloc((size_t)4096 * 512 * 2);
    float* lamv = (float*)alloc((size_t)4096 * 512 * 4);
    ushort* lamvT = (ushort*)alloc((size_t)4 * 512 * 1024 * 2);
    ushort* Sc = (ushort*)alloc((size_t)4 * 8192 * 1024 * 2);  // aliased: Acat after attnv
    float* yout_unused = nullptr; (void)yout_unused;
    float* kn = (float*)alloc(4096 * 4);
    float* lamM1 = (float*)alloc(4096 * 4);
    float* qn = (float*)alloc(32768 * 4);
    float* den = (float*)alloc(32768 * 4);
    float* fac12 = (float*)alloc(32768 * 4);
    float* tss = (float*)alloc(32768 * 4);
    float* Asc = (float*)alloc(32768 * 4);
    // aliases (lifetimes disjoint):
    float* Cp = (float*)qh;       // 4 x 4096 x 512 fp32 = 32 MB == qh size
    ushort* Acat = Sc;            // 4096 x 4096 bf16 = 32 MB <= Sc 64 MB

    hipMemsetAsync(den, 0, 32768 * 4, stream);

    // 1. tangent inputs (bf16), one launch
    k_logmap_bf16<<<dim3(4096, 3), 256, 0, stream>>>(query, key, value, tq, tk, tv);

    // 2. weight transposes -> bf16 [N][K]
    k_transpose_f2b<<<dim3(16, 16, 1), 256, 0, stream>>>(Wk, WkT, 512, 512, 0, 0);
    k_transpose_f2b<<<dim3(16, 16, 1), 256, 0, stream>>>(Wv, WvT, 512, 512, 0, 0);
    k_transpose_f2b<<<dim3(16, 16, 8), 256, 0, stream>>>(Wq, WqT, 512, 512, (size_t)512 * 512,
                                                         (size_t)512 * 512);
    k_transpose_f2b<<<dim3(16, 128, 1), 256, 0, stream>>>(Wo, WoT, 4096, 512, 0, 0);

    // 3. all projections, one launch (z: 0=k,1=v,2..9=q heads) -> 1280 blocks
    k_gemm_proj_all<<<dim3(4, 32, 10), 256, 0, stream>>>(tq, tk, tv, WqT, WkT, WvT, bq, bk, bv,
                                                         yq, yk, yv);

    // 4. expmap epilogues + stats
    k_expmap_stats<<<4096, 256, 0, stream>>>(yk, nullptr, kball, kn, 1);
    k_expmap_stats<<<4096, 256, 0, stream>>>(yv, lamv, nullptr, lamM1, 2);
    k_expmap_stats<<<32768, 256, 0, stream>>>(yq, nullptr, qh, qn, 1);
    k_transpose_f2b<<<dim3(16, 32, 4), 256, 0, stream>>>(lamv, lamvT, 1024, 512,
                                                         (size_t)1024 * 512, (size_t)512 * 1024);

    // 5. attention, batched over z -> 2048 / 1024 blocks
    k_gemm_score<<<dim3(8, 64, 4), 256, 0, stream>>>(qh, kball, Sc, den, qn, kn, lamM1, stau);
    k_gemm_attnv<<<dim3(4, 64, 4), 256, 0, stream>>>(Sc, lamvT, den, yq);

    // 6. head post-processing
    k_headnorm<<<32768, 256, 0, stream>>>(yq, fac12, tss);
    k_cat<<<16, 256, 0, stream>>>(tss, fac12, Asc);
    k_scale_cat<<<65536, 256, 0, stream>>>(yq, Asc, Acat);

    // 7. output projection split-K (512 blocks) + fused reduce/expmap
    k_gemm_sk<<<dim3(4, 32, 4), 256, 0, stream>>>(Acat, WoT, Cp);
    k_final_reduce_expmap<<<4096, 256, 0, stream>>>(Cp, bo, out);
}

// Round 4
// 438.829 us; speedup vs baseline: 4.6204x; 1.2871x over previous
//
#include <hip/hip_runtime.h>
#include <math.h>

// Problem constants: B=4, S=1024, D=512, H=8
constexpr int B_ = 4, S_ = 1024, D_ = 512, H_ = 8;
constexpr float EPS_ = 1e-6f;
constexpr float MAXT = 1.0f - 1e-5f;

typedef __attribute__((ext_vector_type(8))) short bf16x8;
typedef __attribute__((ext_vector_type(4))) float f32x4;

__device__ __forceinline__ ushort f2b(float f) {
    unsigned u = __float_as_uint(f);
    unsigned r = u + 0x7fffu + ((u >> 16) & 1u);
    return (ushort)(r >> 16);
}
__device__ __forceinline__ float b2f(ushort h) {
    return __uint_as_float(((unsigned)h) << 16);
}

__device__ __forceinline__ void async16(const ushort* g, ushort* l) {
    __builtin_amdgcn_global_load_lds(
        (const __attribute__((address_space(1))) unsigned int*)g,
        (__attribute__((address_space(3))) unsigned int*)l, 16, 0, 0);
}

// ---------------- block reductions (blockDim.x == 256) ----------------
__device__ __forceinline__ float blk_reduce_sum(float v, float* sm) {
    for (int o = 32; o > 0; o >>= 1) v += __shfl_down(v, o, 64);
    int lane = threadIdx.x & 63, wid = threadIdx.x >> 6;
    if (lane == 0) sm[wid] = v;
    __syncthreads();
    if (threadIdx.x == 0) sm[0] = sm[0] + sm[1] + sm[2] + sm[3];
    __syncthreads();
    float r = sm[0];
    __syncthreads();
    return r;
}

// ---------------- MFMA NT-GEMM core: C(128x128) = A[128xK] * B[128xK]^T ----------------
__device__ __forceinline__ void gemm_core(const ushort* __restrict__ A,
                                          const ushort* __restrict__ B,
                                          int lda, int ldb, int K, int m0, int n0,
                                          ushort* As, ushort* Bs, f32x4 acc[4][4]) {
    const int tid = threadIdx.x;
    const int w = tid >> 6, lane = tid & 63;
    const int wm = w >> 1, wn = w & 1;
    const int quad = lane >> 4, lx = lane & 15;

    int r1 = w * 32 + (lane >> 2);
    int r2 = r1 + 16;
    int c = lane & 3;
    int q1 = c ^ ((r1 >> 1) & 3);
    int q2 = c ^ ((r2 >> 1) & 3);
    const ushort* a1 = A + (size_t)(m0 + r1) * lda + q1 * 8;
    const ushort* a2 = A + (size_t)(m0 + r2) * lda + q2 * 8;
    const ushort* b1 = B + (size_t)(n0 + r1) * ldb + q1 * 8;
    const ushort* b2 = B + (size_t)(n0 + r2) * ldb + q2 * 8;
    ushort* lA1 = As + (size_t)(w * 32) * 32;
    ushort* lA2 = As + (size_t)(w * 32 + 16) * 32;
    ushort* lB1 = Bs + (size_t)(w * 32) * 32;
    ushort* lB2 = Bs + (size_t)(w * 32 + 16) * 32;

    int raOff[4], rbOff[4];
#pragma unroll
    for (int i = 0; i < 4; i++) {
        int ra = wm * 64 + i * 16 + lx;
        raOff[i] = ra * 32 + (quad ^ ((ra >> 1) & 3)) * 8;
        int rb = wn * 64 + i * 16 + lx;
        rbOff[i] = rb * 32 + (quad ^ ((rb >> 1) & 3)) * 8;
    }
#pragma unroll
    for (int i = 0; i < 4; i++)
#pragma unroll
        for (int j = 0; j < 4; j++) acc[i][j] = (f32x4)(0.0f);

    for (int k0 = 0; k0 < K; k0 += 32) {
        __syncthreads();
        async16(a1 + k0, lA1);
        async16(a2 + k0, lA2);
        async16(b1 + k0, lB1);
        async16(b2 + k0, lB2);
        asm volatile("s_waitcnt vmcnt(0)" ::: "memory");
        __syncthreads();
        bf16x8 af[4], bfr[4];
#pragma unroll
        for (int i = 0; i < 4; i++) af[i] = *(const bf16x8*)(As + raOff[i]);
#pragma unroll
        for (int j = 0; j < 4; j++) bfr[j] = *(const bf16x8*)(Bs + rbOff[j]);
#pragma unroll
        for (int i = 0; i < 4; i++)
#pragma unroll
            for (int j = 0; j < 4; j++)
                acc[i][j] = __builtin_amdgcn_mfma_f32_16x16x32_bf16(af[i], bfr[j], acc[i][j], 0, 0, 0);
    }
}

// ---------------- fused q/k/v projection: z=0 -> K proj, z=1 -> V proj, z>=2 -> Q head z-2 ----------------
__global__ __launch_bounds__(256) void k_gemm_proj_all(const ushort* __restrict__ tq,
                                                       const ushort* __restrict__ tk,
                                                       const ushort* __restrict__ tv,
                                                       const ushort* __restrict__ WqT,
                                                       const ushort* __restrict__ WkT,
                                                       const ushort* __restrict__ WvT,
                                                       const float* __restrict__ bq,
                                                       const float* __restrict__ bk,
                                                       const float* __restrict__ bv,
                                                       float* __restrict__ yq,
                                                       float* __restrict__ yk,
                                                       float* __restrict__ yv) {
    __shared__ ushort As[128 * 32], Bs[128 * 32];
    int z = blockIdx.z;
    const ushort* A;
    const ushort* BT;
    const float* bias;
    float* C;
    int remap = 0, h = 0;
    if (z == 0) { A = tk; BT = WkT; bias = bk; C = yk; }
    else if (z == 1) { A = tv; BT = WvT; bias = bv; C = yv; }
    else {
        h = z - 2;
        A = tq; BT = WqT + (size_t)h * 512 * 512; bias = bq + (size_t)h * 512;
        C = yq; remap = 1;
    }
    f32x4 acc[4][4];
    int m0 = blockIdx.y * 128, n0 = blockIdx.x * 128;
    gemm_core(A, BT, 512, 512, 512, m0, n0, As, Bs, acc);
    int tid = threadIdx.x, w = tid >> 6, lane = tid & 63;
    int wm = w >> 1, wn = w & 1, quad = lane >> 4, lx = lane & 15;
#pragma unroll
    for (int i = 0; i < 4; i++)
#pragma unroll
        for (int reg = 0; reg < 4; reg++) {
            int m = m0 + wm * 64 + i * 16 + quad * 4 + reg;
            size_t orow = remap ? (size_t)((m >> 10) * H_ + h) * S_ + (m & 1023) : (size_t)m;
#pragma unroll
            for (int j = 0; j < 4; j++) {
                int n = n0 + wn * 64 + j * 16 + lx;
                C[orow * 512 + n] = acc[i][j][reg] + bias[n];
            }
        }
}

// ---------------- score GEMM (batched over z): dist -> E bf16, den atomic ----------------
// e = exp(-itau*acosh(arg)) = t^(-itau), t = arg+sqrt(arg^2-1); arg=1+w, w=2*sq/dn
// => e = exp2(-itau * log2(1 + w + sqrt(w*(w+2))))   [hw v_sqrt/v_log/v_exp/v_rcp]
__global__ __launch_bounds__(256) void k_gemm_score(const ushort* __restrict__ Aq,
                                                    const ushort* __restrict__ Bk,
                                                    ushort* __restrict__ E,
                                                    float* __restrict__ den,
                                                    const float* __restrict__ qn,
                                                    const float* __restrict__ kn,
                                                    const float* __restrict__ lamM1,
                                                    const float* __restrict__ stau) {
    __shared__ ushort As[128 * 32], Bs[128 * 32];
    int b = blockIdx.z;
    Aq += (size_t)b * 8192 * 512;
    Bk += (size_t)b * 1024 * 512;
    E += (size_t)b * 8192 * 1024;
    den += (size_t)b * 8192;
    qn += (size_t)b * 8192;
    kn += (size_t)b * 1024;
    lamM1 += (size_t)b * 1024;
    f32x4 acc[4][4];
    int m0 = blockIdx.y * 128, n0 = blockIdx.x * 128;
    gemm_core(Aq, Bk, 512, 512, 512, m0, n0, As, Bs, acc);
    float itau = expf(stau[0]);
    int tid = threadIdx.x, w_ = tid >> 6, lane = tid & 63;
    int wm = w_ >> 1, wn = w_ & 1, quad = lane >> 4, lx = lane & 15;
    float knv[4], okn[4], lmv[4];
#pragma unroll
    for (int j = 0; j < 4; j++) {
        int n = n0 + wn * 64 + j * 16 + lx;
        knv[j] = kn[n];
        okn[j] = 1.0f - knv[j];
        lmv[j] = lamM1[n];
    }
#pragma unroll
    for (int i = 0; i < 4; i++)
#pragma unroll
        for (int reg = 0; reg < 4; reg++) {
            int m = m0 + wm * 64 + i * 16 + quad * 4 + reg;
            float q = qn[m];
            float omq = 1.0f - q;
            float rsum = 0.0f;
#pragma unroll
            for (int j = 0; j < 4; j++) {
                float dot = acc[i][j][reg];
                float sq = fmaxf(q + knv[j] - 2.0f * dot, 0.0f);
                float dn = fmaxf(omq * okn[j], EPS_);
                float w = fmaxf(2.0f * sq * __builtin_amdgcn_rcpf(dn), 1e-7f);
                float root = __builtin_amdgcn_sqrtf(w * (w + 2.0f));
                float t = 1.0f + w + root;
                float e = __builtin_amdgcn_exp2f(-itau * __builtin_amdgcn_logf(t));
                ushort eb = f2b(e);
                int n = n0 + wn * 64 + j * 16 + lx;
                E[(size_t)m * 1024 + n] = eb;
                rsum += b2f(eb) * lmv[j];
            }
            for (int o = 8; o; o >>= 1) rsum += __shfl_xor(rsum, o, 64);
            if (lx == 0) atomicAdd(&den[m], rsum);
        }
}

// ---------------- attn x V GEMM (batched over z): U = (E * lamV^T) / den ----------------
__global__ __launch_bounds__(256) void k_gemm_attnv(const ushort* __restrict__ E,
                                                    const ushort* __restrict__ VT,
                                                    const float* __restrict__ den,
                                                    float* __restrict__ U) {
    __shared__ ushort As[128 * 32], Bs[128 * 32];
    int b = blockIdx.z;
    E += (size_t)b * 8192 * 1024;
    VT += (size_t)b * 512 * 1024;
    den += (size_t)b * 8192;
    U += (size_t)b * 8192 * 512;
    f32x4 acc[4][4];
    int m0 = blockIdx.y * 128, n0 = blockIdx.x * 128;
    gemm_core(E, VT, 1024, 1024, 1024, m0, n0, As, Bs, acc);
    int tid = threadIdx.x, w = tid >> 6, lane = tid & 63;
    int wm = w >> 1, wn = w & 1, quad = lane >> 4, lx = lane & 15;
#pragma unroll
    for (int i = 0; i < 4; i++)
#pragma unroll
        for (int reg = 0; reg < 4; reg++) {
            int m = m0 + wm * 64 + i * 16 + quad * 4 + reg;
            float inv = 1.0f / fmaxf(den[m], EPS_);
#pragma unroll
            for (int j = 0; j < 4; j++) {
                int n = n0 + wn * 64 + j * 16 + lx;
                U[(size_t)m * 512 + n] = acc[i][j][reg] * inv;
            }
        }
}

// ---------------- final GEMM split-K ----------------
__global__ __launch_bounds__(256) void k_gemm_sk(const ushort* __restrict__ Acat,
                                                 const ushort* __restrict__ WoT,
                                                 float* __restrict__ Cp) {
    __shared__ ushort As[128 * 32], Bs[128 * 32];
    int z = blockIdx.z;
    const ushort* A = Acat + (size_t)z * 1024;
    const ushort* BT = WoT + (size_t)z * 1024;
    float* C = Cp + (size_t)z * 4096 * 512;
    f32x4 acc[4][4];
    int m0 = blockIdx.y * 128, n0 = blockIdx.x * 128;
    gemm_core(A, BT, 4096, 4096, 1024, m0, n0, As, Bs, acc);
    int tid = threadIdx.x, w = tid >> 6, lane = tid & 63;
    int wm = w >> 1, wn = w & 1, quad = lane >> 4, lx = lane & 15;
#pragma unroll
    for (int i = 0; i < 4; i++)
#pragma unroll
        for (int reg = 0; reg < 4; reg++) {
            int m = m0 + wm * 64 + i * 16 + quad * 4 + reg;
#pragma unroll
            for (int j = 0; j < 4; j++) {
                int n = n0 + wn * 64 + j * 16 + lx;
                C[(size_t)m * 512 + n] = acc[i][j][reg];
            }
        }
}

// ---------------- final reduce (4 partials + bias) + expmap0 -> out ----------------
__global__ __launch_bounds__(256) void k_final_reduce_expmap(const float* __restrict__ Cp,
                                                             const float* __restrict__ bo,
                                                             float* __restrict__ out) {
    __shared__ float sm[8];
    int r = blockIdx.x;
    float v0 = bo[threadIdx.x], v1 = bo[threadIdx.x + 256];
#pragma unroll
    for (int z = 0; z < 4; z++) {
        const float* row = Cp + ((size_t)z * 4096 + r) * 512;
        v0 += row[threadIdx.x];
        v1 += row[threadIdx.x + 256];
    }
    float ss = blk_reduce_sum(v0 * v0 + v1 * v1, sm);
    float n = sqrtf(fmaxf(ss, EPS_));
    float f = tanhf(n) / n;
    float* o = out + (size_t)r * D_;
    o[threadIdx.x] = f * v0;
    o[threadIdx.x + 256] = f * v1;
}

// ---------------- logmap0 rows -> bf16 tangent (y selects q/k/v) ----------------
__global__ __launch_bounds__(256) void k_logmap_bf16(const float* __restrict__ q,
                                                     const float* __restrict__ k,
                                                     const float* __restrict__ v,
                                                     ushort* __restrict__ tq,
                                                     ushort* __restrict__ tk,
                                                     ushort* __restrict__ tv) {
    __shared__ float sm[8];
    const float* x = (blockIdx.y == 0) ? q : (blockIdx.y == 1) ? k : v;
    ushort* t = (blockIdx.y == 0) ? tq : (blockIdx.y == 1) ? tk : tv;
    int r = blockIdx.x;
    const float* xr = x + (size_t)r * D_;
    float v0 = xr[threadIdx.x], v1 = xr[threadIdx.x + 256];
    float ss = blk_reduce_sum(v0 * v0 + v1 * v1, sm);
    float n = sqrtf(fmaxf(ss, EPS_));
    float f = atanhf(fminf(n, MAXT)) / n;
    ushort* tr = t + (size_t)r * D_;
    tr[threadIdx.x] = f2b(f * v0);
    tr[threadIdx.x + 256] = f2b(f * v1);
}

// ---------------- expmap rows with stats ----------------
__global__ __launch_bounds__(256) void k_expmap_stats(const float* __restrict__ y,
                                                      float* __restrict__ outf,
                                                      ushort* __restrict__ outb,
                                                      float* __restrict__ aux, int mode) {
    __shared__ float sm[8];
    int r = blockIdx.x;
    const float* yr = y + (size_t)r * D_;
    float v0 = yr[threadIdx.x], v1 = yr[threadIdx.x + 256];
    float ss = blk_reduce_sum(v0 * v0 + v1 * v1, sm);
    float n = sqrtf(fmaxf(ss, EPS_));
    float f = tanhf(n) / n;
    ushort h0 = f2b(f * v0), h1 = f2b(f * v1);
    float x0 = b2f(h0), x1 = b2f(h1);
    float ss2 = blk_reduce_sum(x0 * x0 + x1 * x1, sm);
    float bn2 = fminf(ss2, MAXT);
    if (mode == 1) {
        ushort* o = outb + (size_t)r * D_;
        o[threadIdx.x] = h0;
        o[threadIdx.x + 256] = h1;
        if (threadIdx.x == 0) aux[r] = bn2;
    } else {
        float lam = 2.0f / (1.0f - bn2);
        float* o = outf + (size_t)r * D_;
        o[threadIdx.x] = lam * x0;
        o[threadIdx.x + 256] = lam * x1;
        if (threadIdx.x == 0) aux[r] = lam - 1.0f;
    }
}

// ---------------- transpose fp32 [R][C] -> bf16 [C][R] ----------------
__global__ __launch_bounds__(256) void k_transpose_f2b(const float* __restrict__ in,
                                                       ushort* __restrict__ out, int R, int C,
                                                       size_t zin, size_t zout) {
    __shared__ float t[32][33];
    in += (size_t)blockIdx.z * zin;
    out += (size_t)blockIdx.z * zout;
    int c0 = blockIdx.x * 32, r0 = blockIdx.y * 32;
    int tx = threadIdx.x & 31, ty = threadIdx.x >> 5;
    for (int rr = ty; rr < 32; rr += 8) t[rr][tx] = in[(size_t)(r0 + rr) * C + c0 + tx];
    __syncthreads();
    for (int rr = ty; rr < 32; rr += 8)
        out[(size_t)(c0 + rr) * R + r0 + tx] = f2b(t[tx][rr]);
}

// ---------------- per-(b,h,s): mobius 0.5-mul + logmap factors ----------------
__global__ __launch_bounds__(256) void k_headnorm(const float* __restrict__ U,
                                                  float* __restrict__ fac12,
                                                  float* __restrict__ tss) {
    __shared__ float sm[8];
    int r = blockIdx.x;
    const float* ur = U + (size_t)r * D_;
    float v0 = ur[threadIdx.x], v1 = ur[threadIdx.x + 256];
    float ss = blk_reduce_sum(v0 * v0 + v1 * v1, sm);
    if (threadIdx.x == 0) {
        float n = sqrtf(fmaxf(ss, EPS_));
        float a = 0.5f * atanhf(fminf(n, MAXT));
        float f1 = tanhf(a) / n;
        float mss = f1 * f1 * ss;
        float nm = sqrtf(fmaxf(mss, EPS_));
        float f2 = atanhf(fminf(nm, MAXT)) / nm;
        float f12 = f1 * f2;
        fac12[r] = f12;
        tss[r] = f12 * f12 * ss;
    }
}

// ---------------- per-(b,s): concat expmap+logmap collapse -> Ascale ----------------
__global__ __launch_bounds__(256) void k_cat(const float* __restrict__ tss,
                                             const float* __restrict__ fac12,
                                             float* __restrict__ Asc) {
    int idx = blockIdx.x * blockDim.x + threadIdx.x;
    if (idx >= B_ * S_) return;
    int b = idx >> 10, s = idx & 1023;
    int base = b * H_ * S_ + s;
    float sum = 0.0f;
#pragma unroll
    for (int h = 0; h < H_; h++) sum += tss[base + h * S_];
    float nc = sqrtf(fmaxf(sum, EPS_));
    float f3 = tanhf(nc) / nc;
    float css = f3 * f3 * sum;
    float nc2 = sqrtf(fmaxf(css, EPS_));
    float f4 = atanhf(fminf(nc2, MAXT)) / nc2;
    float g = f3 * f4;
#pragma unroll
    for (int h = 0; h < H_; h++) {
        int rr = base + h * S_;
        Asc[rr] = fac12[rr] * g;
    }
}

// ---------------- build concat-A bf16: Acat[(b,s), h*512+d] = Asc*U ----------------
__global__ __launch_bounds__(256) void k_scale_cat(const float* __restrict__ U,
                                                   const float* __restrict__ Asc,
                                                   ushort* __restrict__ Acat) {
    int idx = blockIdx.x * 256 + threadIdx.x;
    int d = idx & 511, h = (idx >> 9) & 7, s = (idx >> 12) & 1023, bb = idx >> 22;
    int urow = (bb * H_ + h) * S_ + s;
    Acat[idx] = f2b(Asc[urow] * U[(size_t)urow * 512 + d]);
}

extern "C" void kernel_launch(void* const* d_in, const int* in_sizes, int n_in,
                              void* d_out, int out_size, void* d_ws, size_t ws_size,
                              hipStream_t stream) {
    (void)in_sizes; (void)n_in; (void)out_size; (void)ws_size;
    const float* query = (const float*)d_in[0];
    const float* key = (const float*)d_in[1];
    const float* value = (const float*)d_in[2];
    const float* Wq = (const float*)d_in[3];
    const float* bq = (const float*)d_in[4];
    const float* Wk = (const float*)d_in[5];
    const float* bk = (const float*)d_in[6];
    const float* Wv = (const float*)d_in[7];
    const float* bv = (const float*)d_in[8];
    const float* Wo = (const float*)d_in[9];
    const float* bo = (const float*)d_in[10];
    const float* stau = (const float*)d_in[11];
    float* out = (float*)d_out;

    char* p = (char*)d_ws;
    auto alloc = [&](size_t bytes) {
        char* r = p;
        p += (bytes + 255) & ~(size_t)255;
        return r;
    };
    ushort* tq = (ushort*)alloc((size_t)4096 * 512 * 2);
    ushort* tk = (ushort*)alloc((size_t)4096 * 512 * 2);
    ushort* tv = (ushort*)alloc((size_t)4096 * 512 * 2);
    ushort* WqT = (ushort*)alloc((size_t)8 * 512 * 512 * 2);
    ushort* WkT = (ushort*)alloc((size_t)512 * 512 * 2);
    ushort* WvT = (ushort*)alloc((size_t)512 * 512 * 2);
    ushort* WoT = (ushort*)alloc((size_t)4096 * 512 * 2);
    float* yq = (float*)alloc((size_t)32768 * 512 * 4);  // also U after attnv
    float* yk = (float*)alloc((size_t)4096 * 512 * 4);
    float* yv = (float*)alloc((size_t)4096 * 512 * 4);
    ushort* qh = (ushort*)alloc((size_t)32768 * 512 * 2);  // aliased: Cp partials
    ushort* kball = (ushort*)alloc((size_t)4096 * 512 * 2);
    float* lamv = (float*)alloc((size_t)4096 * 512 * 4);
    ushort* lamvT = (ushort*)alloc((size_t)4 * 512 * 1024 * 2);
    ushort* Sc = (ushort*)alloc((size_t)4 * 8192 * 1024 * 2);  // aliased: Acat
    float* kn = (float*)alloc(4096 * 4);
    float* lamM1 = (float*)alloc(4096 * 4);
    float* qn = (float*)alloc(32768 * 4);
    float* den = (float*)alloc(32768 * 4);
    float* fac12 = (float*)alloc(32768 * 4);
    float* tss = (float*)alloc(32768 * 4);
    float* Asc = (float*)alloc(32768 * 4);
    float* Cp = (float*)qh;
    ushort* Acat = Sc;

    hipMemsetAsync(den, 0, 32768 * 4, stream);

    // 1. tangent inputs (bf16), one launch
    k_logmap_bf16<<<dim3(4096, 3), 256, 0, stream>>>(query, key, value, tq, tk, tv);

    // 2. weight transposes -> bf16 [N][K]
    k_transpose_f2b<<<dim3(16, 16, 1), 256, 0, stream>>>(Wk, WkT, 512, 512, 0, 0);
    k_transpose_f2b<<<dim3(16, 16, 1), 256, 0, stream>>>(Wv, WvT, 512, 512, 0, 0);
    k_transpose_f2b<<<dim3(16, 16, 8), 256, 0, stream>>>(Wq, WqT, 512, 512, (size_t)512 * 512,
                                                         (size_t)512 * 512);
    k_transpose_f2b<<<dim3(16, 128, 1), 256, 0, stream>>>(Wo, WoT, 4096, 512, 0, 0);

    // 3. all projections, one launch (z: 0=k,1=v,2..9=q heads)
    k_gemm_proj_all<<<dim3(4, 32, 10), 256, 0, stream>>>(tq, tk, tv, WqT, WkT, WvT, bq, bk, bv,
                                                         yq, yk, yv);

    // 4. expmap epilogues + stats
    k_expmap_stats<<<4096, 256, 0, stream>>>(yk, nullptr, kball, kn, 1);
    k_expmap_stats<<<4096, 256, 0, stream>>>(yv, lamv, nullptr, lamM1, 2);
    k_expmap_stats<<<32768, 256, 0, stream>>>(yq, nullptr, qh, qn, 1);
    k_transpose_f2b<<<dim3(16, 32, 4), 256, 0, stream>>>(lamv, lamvT, 1024, 512,
                                                         (size_t)1024 * 512, (size_t)512 * 1024);

    // 5. attention, batched over z
    k_gemm_score<<<dim3(8, 64, 4), 256, 0, stream>>>(qh, kball, Sc, den, qn, kn, lamM1, stau);
    k_gemm_attnv<<<dim3(4, 64, 4), 256, 0, stream>>>(Sc, lamvT, den, yq);

    // 6. head post-processing
    k_headnorm<<<32768, 256, 0, stream>>>(yq, fac12, tss);
    k_cat<<<16, 256, 0, stream>>>(tss, fac12, Asc);
    k_scale_cat<<<65536, 256, 0, stream>>>(yq, Asc, Acat);

    // 7. output projection split-K + fused reduce/expmap
    k_gemm_sk<<<dim3(4, 32, 4), 256, 0, stream>>>(Acat, WoT, Cp);
    k_final_reduce_expmap<<<4096, 256, 0, stream>>>(Cp, bo, out);
}

// Round 5
// 405.867 us; speedup vs baseline: 4.9956x; 1.0812x over previous
//
#include <hip/hip_runtime.h>
#include <math.h>

// Problem constants: B=4, S=1024, D=512, H=8
constexpr int B_ = 4, S_ = 1024, D_ = 512, H_ = 8;
constexpr float EPS_ = 1e-6f;
constexpr float MAXT = 1.0f - 1e-5f;

typedef __attribute__((ext_vector_type(8))) short bf16x8;
typedef __attribute__((ext_vector_type(4))) float f32x4;

__device__ __forceinline__ ushort f2b(float f) {
    unsigned u = __float_as_uint(f);
    unsigned r = u + 0x7fffu + ((u >> 16) & 1u);
    return (ushort)(r >> 16);
}
__device__ __forceinline__ float b2f(ushort h) {
    return __uint_as_float(((unsigned)h) << 16);
}

__device__ __forceinline__ void async16(const ushort* g, ushort* l) {
    __builtin_amdgcn_global_load_lds(
        (const __attribute__((address_space(1))) unsigned int*)g,
        (__attribute__((address_space(3))) unsigned int*)l, 16, 0, 0);
}

// ---------------- block reductions (blockDim.x == 256) ----------------
__device__ __forceinline__ float blk_reduce_sum(float v, float* sm) {
    for (int o = 32; o > 0; o >>= 1) v += __shfl_down(v, o, 64);
    int lane = threadIdx.x & 63, wid = threadIdx.x >> 6;
    if (lane == 0) sm[wid] = v;
    __syncthreads();
    if (threadIdx.x == 0) sm[0] = sm[0] + sm[1] + sm[2] + sm[3];
    __syncthreads();
    float r = sm[0];
    __syncthreads();
    return r;
}

// ---------------- MFMA NT-GEMM core 256x128: C = A[256xK] * B[128xK]^T ----------------
// 4 waves; wave w computes rows [w*64, w*64+64) x all 128 cols. acc[i][j]: i m-frag, j n-frag.
// LDS As[256][32], Bs[128][32] bf16 with XOR chunk swizzle (16B slot s of row r holds chunk s^((r>>1)&3)).
__device__ __forceinline__ void gemm_core256(const ushort* __restrict__ A,
                                             const ushort* __restrict__ B,
                                             int lda, int ldb, int K, int m0, int n0,
                                             ushort* As, ushort* Bs, f32x4 acc[4][8]) {
    const int tid = threadIdx.x;
    const int w = tid >> 6, lane = tid & 63;
    const int quad = lane >> 4, lx = lane & 15;
    const int rr = lane >> 2, c = lane & 3;

    // staging: wave w stages A rows [w*64, w*64+64) in 4 issues, B rows [w*32, w*32+32) in 2 issues
    const ushort* aP[4];
    ushort* lAp[4];
#pragma unroll
    for (int i = 0; i < 4; i++) {
        int r = w * 64 + i * 16 + rr;
        int q = c ^ ((r >> 1) & 3);
        aP[i] = A + (size_t)(m0 + r) * lda + q * 8;
        lAp[i] = As + (w * 64 + i * 16) * 32;
    }
    const ushort* bP[2];
    ushort* lBp[2];
#pragma unroll
    for (int i = 0; i < 2; i++) {
        int r = w * 32 + i * 16 + rr;
        int q = c ^ ((r >> 1) & 3);
        bP[i] = B + (size_t)(n0 + r) * ldb + q * 8;
        lBp[i] = Bs + (w * 32 + i * 16) * 32;
    }

    int raOff[4], rbOff[8];
#pragma unroll
    for (int i = 0; i < 4; i++) {
        int ra = w * 64 + i * 16 + lx;
        raOff[i] = ra * 32 + (quad ^ ((ra >> 1) & 3)) * 8;
    }
#pragma unroll
    for (int j = 0; j < 8; j++) {
        int rb = j * 16 + lx;
        rbOff[j] = rb * 32 + (quad ^ ((rb >> 1) & 3)) * 8;
    }
#pragma unroll
    for (int i = 0; i < 4; i++)
#pragma unroll
        for (int j = 0; j < 8; j++) acc[i][j] = (f32x4)(0.0f);

    for (int k0 = 0; k0 < K; k0 += 32) {
        __syncthreads();
        async16(aP[0] + k0, lAp[0]);
        async16(aP[1] + k0, lAp[1]);
        async16(aP[2] + k0, lAp[2]);
        async16(aP[3] + k0, lAp[3]);
        async16(bP[0] + k0, lBp[0]);
        async16(bP[1] + k0, lBp[1]);
        asm volatile("s_waitcnt vmcnt(0)" ::: "memory");
        __syncthreads();
        bf16x8 af[4], bfr[8];
#pragma unroll
        for (int i = 0; i < 4; i++) af[i] = *(const bf16x8*)(As + raOff[i]);
#pragma unroll
        for (int j = 0; j < 8; j++) bfr[j] = *(const bf16x8*)(Bs + rbOff[j]);
#pragma unroll
        for (int i = 0; i < 4; i++)
#pragma unroll
            for (int j = 0; j < 8; j++)
                acc[i][j] = __builtin_amdgcn_mfma_f32_16x16x32_bf16(af[i], bfr[j], acc[i][j], 0, 0, 0);
    }
}

// ---------------- fused q/k/v projection: z=0 K, z=1 V, z>=2 Q head z-2 ----------------
__global__ __launch_bounds__(256, 2) void k_gemm_proj_all(const ushort* __restrict__ tq,
                                                          const ushort* __restrict__ tk,
                                                          const ushort* __restrict__ tv,
                                                          const ushort* __restrict__ WqT,
                                                          const ushort* __restrict__ WkT,
                                                          const ushort* __restrict__ WvT,
                                                          const float* __restrict__ bq,
                                                          const float* __restrict__ bk,
                                                          const float* __restrict__ bv,
                                                          float* __restrict__ yq,
                                                          float* __restrict__ yk,
                                                          float* __restrict__ yv) {
    __shared__ ushort As[256 * 32], Bs[128 * 32];
    int z = blockIdx.z;
    const ushort* A;
    const ushort* BT;
    const float* bias;
    float* C;
    int remap = 0, h = 0;
    if (z == 0) { A = tk; BT = WkT; bias = bk; C = yk; }
    else if (z == 1) { A = tv; BT = WvT; bias = bv; C = yv; }
    else {
        h = z - 2;
        A = tq; BT = WqT + (size_t)h * 512 * 512; bias = bq + (size_t)h * 512;
        C = yq; remap = 1;
    }
    f32x4 acc[4][8];
    int m0 = blockIdx.y * 256, n0 = blockIdx.x * 128;
    gemm_core256(A, BT, 512, 512, 512, m0, n0, As, Bs, acc);
    int tid = threadIdx.x, w = tid >> 6, lane = tid & 63;
    int quad = lane >> 4, lx = lane & 15;
#pragma unroll
    for (int i = 0; i < 4; i++)
#pragma unroll
        for (int reg = 0; reg < 4; reg++) {
            int m = m0 + w * 64 + i * 16 + quad * 4 + reg;
            size_t orow = remap ? (size_t)((m >> 10) * H_ + h) * S_ + (m & 1023) : (size_t)m;
#pragma unroll
            for (int j = 0; j < 8; j++) {
                int n = n0 + j * 16 + lx;
                C[orow * 512 + n] = acc[i][j][reg] + bias[n];
            }
        }
}

// ---------------- score GEMM (batched over z): dist -> E bf16, den atomic ----------------
// e = t^(-itau) = exp2(-itau*log2(1+w+sqrt(w*(w+2)))), w = 2*sq/dn
__global__ __launch_bounds__(256, 2) void k_gemm_score(const ushort* __restrict__ Aq,
                                                       const ushort* __restrict__ Bk,
                                                       ushort* __restrict__ E,
                                                       float* __restrict__ den,
                                                       const float* __restrict__ qn,
                                                       const float* __restrict__ kn,
                                                       const float* __restrict__ lamM1,
                                                       const float* __restrict__ stau) {
    __shared__ ushort As[256 * 32], Bs[128 * 32];
    int b = blockIdx.z;
    Aq += (size_t)b * 8192 * 512;
    Bk += (size_t)b * 1024 * 512;
    E += (size_t)b * 8192 * 1024;
    den += (size_t)b * 8192;
    qn += (size_t)b * 8192;
    kn += (size_t)b * 1024;
    lamM1 += (size_t)b * 1024;
    f32x4 acc[4][8];
    int m0 = blockIdx.y * 256, n0 = blockIdx.x * 128;
    gemm_core256(Aq, Bk, 512, 512, 512, m0, n0, As, Bs, acc);
    float itau = expf(stau[0]);
    int tid = threadIdx.x, w_ = tid >> 6, lane = tid & 63;
    int quad = lane >> 4, lx = lane & 15;
    float knv[8], okn[8], lmv[8];
#pragma unroll
    for (int j = 0; j < 8; j++) {
        int n = n0 + j * 16 + lx;
        knv[j] = kn[n];
        okn[j] = 1.0f - knv[j];
        lmv[j] = lamM1[n];
    }
#pragma unroll
    for (int i = 0; i < 4; i++)
#pragma unroll
        for (int reg = 0; reg < 4; reg++) {
            int m = m0 + w_ * 64 + i * 16 + quad * 4 + reg;
            float q = qn[m];
            float omq = 1.0f - q;
            float rsum = 0.0f;
#pragma unroll
            for (int j = 0; j < 8; j++) {
                float dot = acc[i][j][reg];
                float sq = fmaxf(q + knv[j] - 2.0f * dot, 0.0f);
                float dn = fmaxf(omq * okn[j], EPS_);
                float w = fmaxf(2.0f * sq * __builtin_amdgcn_rcpf(dn), 1e-7f);
                float root = __builtin_amdgcn_sqrtf(w * (w + 2.0f));
                float t = 1.0f + w + root;
                float e = __builtin_amdgcn_exp2f(-itau * __builtin_amdgcn_logf(t));
                ushort eb = f2b(e);
                int n = n0 + j * 16 + lx;
                E[(size_t)m * 1024 + n] = eb;
                rsum += b2f(eb) * lmv[j];
            }
            for (int o = 8; o; o >>= 1) rsum += __shfl_xor(rsum, o, 64);
            if (lx == 0) atomicAdd(&den[m], rsum);
        }
}

// ---------------- attn x V GEMM (batched over z): u = (E*lamV^T)/den -> bf16 U + atomic ss ----------------
__global__ __launch_bounds__(256, 2) void k_gemm_attnv(const ushort* __restrict__ E,
                                                       const ushort* __restrict__ VT,
                                                       const float* __restrict__ den,
                                                       ushort* __restrict__ Ub,
                                                       float* __restrict__ ssU) {
    __shared__ ushort As[256 * 32], Bs[128 * 32];
    int b = blockIdx.z;
    E += (size_t)b * 8192 * 1024;
    VT += (size_t)b * 512 * 1024;
    den += (size_t)b * 8192;
    Ub += (size_t)b * 8192 * 512;
    ssU += (size_t)b * 8192;
    f32x4 acc[4][8];
    int m0 = blockIdx.y * 256, n0 = blockIdx.x * 128;
    gemm_core256(E, VT, 1024, 1024, 1024, m0, n0, As, Bs, acc);
    int tid = threadIdx.x, w = tid >> 6, lane = tid & 63;
    int quad = lane >> 4, lx = lane & 15;
#pragma unroll
    for (int i = 0; i < 4; i++)
#pragma unroll
        for (int reg = 0; reg < 4; reg++) {
            int m = m0 + w * 64 + i * 16 + quad * 4 + reg;
            float inv = 1.0f / fmaxf(den[m], EPS_);
            float ssum = 0.0f;
#pragma unroll
            for (int j = 0; j < 8; j++) {
                int n = n0 + j * 16 + lx;
                float u = acc[i][j][reg] * inv;
                Ub[(size_t)m * 512 + n] = f2b(u);
                ssum += u * u;
            }
            for (int o = 8; o; o >>= 1) ssum += __shfl_xor(ssum, o, 64);
            if (lx == 0) atomicAdd(&ssU[m], ssum);
        }
}

// ---------------- output projection split-K over 8 head-chunks: Cp[z] = U_h @ Wo_h^T ----------------
__global__ __launch_bounds__(256, 2) void k_gemm_sk(const ushort* __restrict__ Ub,
                                                    const ushort* __restrict__ WoT,
                                                    float* __restrict__ Cp) {
    __shared__ ushort As[256 * 32], Bs[128 * 32];
    int z = blockIdx.z;  // head chunk
    int m0 = blockIdx.y * 256, n0 = blockIdx.x * 128;
    int bb = m0 >> 10, s0 = m0 & 1023;
    const ushort* A = Ub + ((size_t)(bb * H_ + z) * S_ + s0) * 512;
    const ushort* BT = WoT + (size_t)z * 512;  // cols [z*512, z*512+512) of k, ldb=4096
    float* C = Cp + (size_t)z * 4096 * 512;
    f32x4 acc[4][8];
    gemm_core256(A, BT, 512, 4096, 512, 0, n0, As, Bs, acc);
    int tid = threadIdx.x, w = tid >> 6, lane = tid & 63;
    int quad = lane >> 4, lx = lane & 15;
#pragma unroll
    for (int i = 0; i < 4; i++)
#pragma unroll
        for (int reg = 0; reg < 4; reg++) {
            int m = m0 + w * 64 + i * 16 + quad * 4 + reg;
#pragma unroll
            for (int j = 0; j < 8; j++) {
                int n = n0 + j * 16 + lx;
                C[(size_t)m * 512 + n] = acc[i][j][reg];
            }
        }
}

// ---------------- hyper factors from row norms: Asc8[(b,s),h] = fac12[h]*g ----------------
__global__ __launch_bounds__(256) void k_hyperfactors(const float* __restrict__ ssU,
                                                      float* __restrict__ Asc8) {
    int idx = blockIdx.x * 256 + threadIdx.x;
    if (idx >= B_ * S_) return;
    int b = idx >> 10, s = idx & 1023;
    float f12[8];
    float sum = 0.0f;
#pragma unroll
    for (int h = 0; h < H_; h++) {
        float ss = ssU[(size_t)(b * H_ + h) * S_ + s];
        float n = sqrtf(fmaxf(ss, EPS_));
        float a = 0.5f * atanhf(fminf(n, MAXT));
        float f1 = tanhf(a) / n;
        float mss = f1 * f1 * ss;
        float nm = sqrtf(fmaxf(mss, EPS_));
        float f2 = atanhf(fminf(nm, MAXT)) / nm;
        f12[h] = f1 * f2;
        sum += f12[h] * f12[h] * ss;
    }
    float nc = sqrtf(fmaxf(sum, EPS_));
    float f3 = tanhf(nc) / nc;
    float css = f3 * f3 * sum;
    float nc2 = sqrtf(fmaxf(css, EPS_));
    float f4 = atanhf(fminf(nc2, MAXT)) / nc2;
    float g = f3 * f4;
#pragma unroll
    for (int h = 0; h < H_; h++) Asc8[(size_t)idx * 8 + h] = f12[h] * g;
}

// ---------------- final reduce: out = expmap0(sum_z Asc8[r,z]*Cp[z][r,:] + bo) ----------------
__global__ __launch_bounds__(256) void k_final_reduce_expmap(const float* __restrict__ Cp,
                                                             const float* __restrict__ Asc8,
                                                             const float* __restrict__ bo,
                                                             float* __restrict__ out) {
    __shared__ float sm[8];
    int r = blockIdx.x;
    float a[8];
#pragma unroll
    for (int z = 0; z < 8; z++) a[z] = Asc8[(size_t)r * 8 + z];
    float v0 = bo[threadIdx.x], v1 = bo[threadIdx.x + 256];
#pragma unroll
    for (int z = 0; z < 8; z++) {
        const float* row = Cp + ((size_t)z * 4096 + r) * 512;
        v0 += a[z] * row[threadIdx.x];
        v1 += a[z] * row[threadIdx.x + 256];
    }
    float ss = blk_reduce_sum(v0 * v0 + v1 * v1, sm);
    float n = sqrtf(fmaxf(ss, EPS_));
    float f = tanhf(n) / n;
    float* o = out + (size_t)r * D_;
    o[threadIdx.x] = f * v0;
    o[threadIdx.x + 256] = f * v1;
}

// ---------------- logmap0 rows -> bf16 tangent (y selects q/k/v) ----------------
__global__ __launch_bounds__(256) void k_logmap_bf16(const float* __restrict__ q,
                                                     const float* __restrict__ k,
                                                     const float* __restrict__ v,
                                                     ushort* __restrict__ tq,
                                                     ushort* __restrict__ tk,
                                                     ushort* __restrict__ tv) {
    __shared__ float sm[8];
    const float* x = (blockIdx.y == 0) ? q : (blockIdx.y == 1) ? k : v;
    ushort* t = (blockIdx.y == 0) ? tq : (blockIdx.y == 1) ? tk : tv;
    int r = blockIdx.x;
    const float* xr = x + (size_t)r * D_;
    float v0 = xr[threadIdx.x], v1 = xr[threadIdx.x + 256];
    float ss = blk_reduce_sum(v0 * v0 + v1 * v1, sm);
    float n = sqrtf(fmaxf(ss, EPS_));
    float f = atanhf(fminf(n, MAXT)) / n;
    ushort* tr = t + (size_t)r * D_;
    tr[threadIdx.x] = f2b(f * v0);
    tr[threadIdx.x + 256] = f2b(f * v1);
}

// ---------------- expmap rows with stats ----------------
// mode 1: bf16 ball + aux=clip(|ball|^2). mode 2: lam*ball fp32 + aux=lam-1.
__global__ __launch_bounds__(256) void k_expmap_stats(const float* __restrict__ y,
                                                      float* __restrict__ outf,
                                                      ushort* __restrict__ outb,
                                                      float* __restrict__ aux, int mode) {
    __shared__ float sm[8];
    int r = blockIdx.x;
    const float* yr = y + (size_t)r * D_;
    float v0 = yr[threadIdx.x], v1 = yr[threadIdx.x + 256];
    float ss = blk_reduce_sum(v0 * v0 + v1 * v1, sm);
    float n = sqrtf(fmaxf(ss, EPS_));
    float f = tanhf(n) / n;
    ushort h0 = f2b(f * v0), h1 = f2b(f * v1);
    float x0 = b2f(h0), x1 = b2f(h1);
    float ss2 = blk_reduce_sum(x0 * x0 + x1 * x1, sm);
    float bn2 = fminf(ss2, MAXT);
    if (mode == 1) {
        ushort* o = outb + (size_t)r * D_;
        o[threadIdx.x] = h0;
        o[threadIdx.x + 256] = h1;
        if (threadIdx.x == 0) aux[r] = bn2;
    } else {
        float lam = 2.0f / (1.0f - bn2);
        float* o = outf + (size_t)r * D_;
        o[threadIdx.x] = lam * x0;
        o[threadIdx.x + 256] = lam * x1;
        if (threadIdx.x == 0) aux[r] = lam - 1.0f;
    }
}

// ---------------- transpose fp32 [R][C] -> bf16 [C][R] ----------------
__global__ __launch_bounds__(256) void k_transpose_f2b(const float* __restrict__ in,
                                                       ushort* __restrict__ out, int R, int C,
                                                       size_t zin, size_t zout) {
    __shared__ float t[32][33];
    in += (size_t)blockIdx.z * zin;
    out += (size_t)blockIdx.z * zout;
    int c0 = blockIdx.x * 32, r0 = blockIdx.y * 32;
    int tx = threadIdx.x & 31, ty = threadIdx.x >> 5;
    for (int rr = ty; rr < 32; rr += 8) t[rr][tx] = in[(size_t)(r0 + rr) * C + c0 + tx];
    __syncthreads();
    for (int rr = ty; rr < 32; rr += 8)
        out[(size_t)(c0 + rr) * R + r0 + tx] = f2b(t[tx][rr]);
}

extern "C" void kernel_launch(void* const* d_in, const int* in_sizes, int n_in,
                              void* d_out, int out_size, void* d_ws, size_t ws_size,
                              hipStream_t stream) {
    (void)in_sizes; (void)n_in; (void)out_size; (void)ws_size;
    const float* query = (const float*)d_in[0];
    const float* key = (const float*)d_in[1];
    const float* value = (const float*)d_in[2];
    const float* Wq = (const float*)d_in[3];
    const float* bq = (const float*)d_in[4];
    const float* Wk = (const float*)d_in[5];
    const float* bk = (const float*)d_in[6];
    const float* Wv = (const float*)d_in[7];
    const float* bv = (const float*)d_in[8];
    const float* Wo = (const float*)d_in[9];
    const float* bo = (const float*)d_in[10];
    const float* stau = (const float*)d_in[11];
    float* out = (float*)d_out;

    char* p = (char*)d_ws;
    auto alloc = [&](size_t bytes) {
        char* r = p;
        p += (bytes + 255) & ~(size_t)255;
        return r;
    };
    ushort* tq = (ushort*)alloc((size_t)4096 * 512 * 2);
    ushort* tk = (ushort*)alloc((size_t)4096 * 512 * 2);
    ushort* tv = (ushort*)alloc((size_t)4096 * 512 * 2);
    ushort* WqT = (ushort*)alloc((size_t)8 * 512 * 512 * 2);
    ushort* WkT = (ushort*)alloc((size_t)512 * 512 * 2);
    ushort* WvT = (ushort*)alloc((size_t)512 * 512 * 2);
    ushort* WoT = (ushort*)alloc((size_t)4096 * 512 * 2);
    float* yq = (float*)alloc((size_t)32768 * 512 * 4);
    float* yk = (float*)alloc((size_t)4096 * 512 * 4);
    float* yv = (float*)alloc((size_t)4096 * 512 * 4);
    ushort* qh = (ushort*)alloc((size_t)32768 * 512 * 2);  // alias: Ub after score consumes qh
    ushort* kball = (ushort*)alloc((size_t)4096 * 512 * 2);
    float* lamv = (float*)alloc((size_t)4096 * 512 * 4);
    ushort* lamvT = (ushort*)alloc((size_t)4 * 512 * 1024 * 2);
    ushort* Sc = (ushort*)alloc((size_t)4 * 8192 * 1024 * 2);  // alias: Cp after attnv consumes E
    float* kn = (float*)alloc(4096 * 4);
    float* lamM1 = (float*)alloc(4096 * 4);
    float* qn = (float*)alloc(32768 * 4);
    float* den = (float*)alloc(32768 * 4);
    float* ssU = (float*)alloc(32768 * 4);  // adjacent to den: one memset covers both
    float* Asc8 = (float*)alloc(32768 * 4);
    ushort* Ub = qh;       // 32 MB, lifetime disjoint (qh fully read by score before attnv writes)
    float* Cp = (float*)Sc;  // 64 MB, lifetime disjoint (E fully read by attnv before sk writes)

    hipMemsetAsync(den, 0, 2 * 32768 * 4, stream);  // den + ssU

    // 1. tangent inputs (bf16)
    k_logmap_bf16<<<dim3(4096, 3), 256, 0, stream>>>(query, key, value, tq, tk, tv);

    // 2. weight transposes -> bf16 [N][K]
    k_transpose_f2b<<<dim3(16, 16, 1), 256, 0, stream>>>(Wk, WkT, 512, 512, 0, 0);
    k_transpose_f2b<<<dim3(16, 16, 1), 256, 0, stream>>>(Wv, WvT, 512, 512, 0, 0);
    k_transpose_f2b<<<dim3(16, 16, 8), 256, 0, stream>>>(Wq, WqT, 512, 512, (size_t)512 * 512,
                                                         (size_t)512 * 512);
    k_transpose_f2b<<<dim3(16, 128, 1), 256, 0, stream>>>(Wo, WoT, 4096, 512, 0, 0);

    // 3. all projections, one launch (z: 0=k,1=v,2..9=q heads), 256x128 tiles
    k_gemm_proj_all<<<dim3(4, 16, 10), 256, 0, stream>>>(tq, tk, tv, WqT, WkT, WvT, bq, bk, bv,
                                                         yq, yk, yv);

    // 4. expmap epilogues + stats
    k_expmap_stats<<<4096, 256, 0, stream>>>(yk, nullptr, kball, kn, 1);
    k_expmap_stats<<<4096, 256, 0, stream>>>(yv, lamv, nullptr, lamM1, 2);
    k_expmap_stats<<<32768, 256, 0, stream>>>(yq, nullptr, qh, qn, 1);
    k_transpose_f2b<<<dim3(16, 32, 4), 256, 0, stream>>>(lamv, lamvT, 1024, 512,
                                                         (size_t)1024 * 512, (size_t)512 * 1024);

    // 5. attention, batched over z
    k_gemm_score<<<dim3(8, 32, 4), 256, 0, stream>>>(qh, kball, Sc, den, qn, kn, lamM1, stau);
    k_gemm_attnv<<<dim3(4, 32, 4), 256, 0, stream>>>(Sc, lamvT, den, Ub, ssU);

    // 6. hyper factors (tiny)
    k_hyperfactors<<<16, 256, 0, stream>>>(ssU, Asc8);

    // 7. output projection split-K over 8 head-chunks + fused scaled-reduce/expmap
    k_gemm_sk<<<dim3(4, 16, 8), 256, 0, stream>>>(Ub, WoT, Cp);
    k_final_reduce_expmap<<<4096, 256, 0, stream>>>(Cp, Asc8, bo, out);
}

// Round 6
// 390.091 us; speedup vs baseline: 5.1976x; 1.0404x over previous
//
#include <hip/hip_runtime.h>
#include <math.h>

// Problem constants: B=4, S=1024, D=512, H=8
constexpr int B_ = 4, S_ = 1024, D_ = 512, H_ = 8;
constexpr float EPS_ = 1e-6f;
constexpr float MAXT = 1.0f - 1e-5f;

typedef __attribute__((ext_vector_type(8))) short bf16x8;
typedef __attribute__((ext_vector_type(4))) float f32x4;

__device__ __forceinline__ ushort f2b(float f) {
    unsigned u = __float_as_uint(f);
    unsigned r = u + 0x7fffu + ((u >> 16) & 1u);
    return (ushort)(r >> 16);
}
__device__ __forceinline__ float b2f(ushort h) {
    return __uint_as_float(((unsigned)h) << 16);
}

__device__ __forceinline__ void async16(const ushort* g, ushort* l) {
    __builtin_amdgcn_global_load_lds(
        (const __attribute__((address_space(1))) unsigned int*)g,
        (__attribute__((address_space(3))) unsigned int*)l, 16, 0, 0);
}

// ---------------- block reductions (blockDim.x == 256) ----------------
__device__ __forceinline__ float blk_reduce_sum(float v, float* sm) {
    for (int o = 32; o > 0; o >>= 1) v += __shfl_down(v, o, 64);
    int lane = threadIdx.x & 63, wid = threadIdx.x >> 6;
    if (lane == 0) sm[wid] = v;
    __syncthreads();
    if (threadIdx.x == 0) sm[0] = sm[0] + sm[1] + sm[2] + sm[3];
    __syncthreads();
    float r = sm[0];
    __syncthreads();
    return r;
}

// ---------------- MFMA NT-GEMM core 256x128, double-buffered K-loop ----------------
// 4 waves; wave w owns rows [w*64, w*64+64) x 128 cols. LDS: 2 buffers of
// (A 256x32 + B 128x32) bf16, XOR chunk swizzle. Pipelined: issue step s+1's
// 6 DMAs, then s_waitcnt vmcnt(6) (waits step s only), raw s_barrier (no drain).
constexpr int GC_ABUF = 256 * 32;            // ushorts
constexpr int GC_BUF = (256 + 128) * 32;     // ushorts per buffer
constexpr int GC_SH = GC_BUF * 2;            // total ushorts (48 KB)

__device__ __forceinline__ void gemm_core256(const ushort* __restrict__ A,
                                             const ushort* __restrict__ B,
                                             int lda, int ldb, int K, int m0, int n0,
                                             ushort* __restrict__ sh, f32x4 acc[4][8]) {
    const int tid = threadIdx.x;
    const int w = tid >> 6, lane = tid & 63;
    const int quad = lane >> 4, lx = lane & 15;
    const int rr = lane >> 2, c = lane & 3;

    const ushort* aP[4];
    int aOff[4];
#pragma unroll
    for (int i = 0; i < 4; i++) {
        int r = w * 64 + i * 16 + rr;
        int q = c ^ ((r >> 1) & 3);
        aP[i] = A + (size_t)(m0 + r) * lda + q * 8;
        aOff[i] = (w * 64 + i * 16) * 32;  // wave-uniform LDS base
    }
    const ushort* bP[2];
    int bOff[2];
#pragma unroll
    for (int i = 0; i < 2; i++) {
        int r = w * 32 + i * 16 + rr;
        int q = c ^ ((r >> 1) & 3);
        bP[i] = B + (size_t)(n0 + r) * ldb + q * 8;
        bOff[i] = GC_ABUF + (w * 32 + i * 16) * 32;
    }

    int raOff[4], rbOff[8];
#pragma unroll
    for (int i = 0; i < 4; i++) {
        int ra = w * 64 + i * 16 + lx;
        raOff[i] = ra * 32 + (quad ^ ((ra >> 1) & 3)) * 8;
    }
#pragma unroll
    for (int j = 0; j < 8; j++) {
        int rb = j * 16 + lx;
        rbOff[j] = GC_ABUF + rb * 32 + (quad ^ ((rb >> 1) & 3)) * 8;
    }
#pragma unroll
    for (int i = 0; i < 4; i++)
#pragma unroll
        for (int j = 0; j < 8; j++) acc[i][j] = (f32x4)(0.0f);

    // prologue: step 0 into buffer 0
#pragma unroll
    for (int i = 0; i < 4; i++) async16(aP[i], sh + aOff[i]);
#pragma unroll
    for (int i = 0; i < 2; i++) async16(bP[i], sh + bOff[i]);

    const int nsteps = K >> 5;
    for (int s = 0; s < nsteps; s++) {
        ushort* cur = sh + (s & 1) * GC_BUF;
        if (s + 1 < nsteps) {
            ushort* nxt = sh + ((s + 1) & 1) * GC_BUF;
            int k0 = (s + 1) << 5;
#pragma unroll
            for (int i = 0; i < 4; i++) async16(aP[i] + k0, nxt + aOff[i]);
#pragma unroll
            for (int i = 0; i < 2; i++) async16(bP[i] + k0, nxt + bOff[i]);
            asm volatile("s_waitcnt vmcnt(6)" ::: "memory");
        } else {
            asm volatile("s_waitcnt vmcnt(0)" ::: "memory");
        }
        asm volatile("s_barrier" ::: "memory");
        bf16x8 af[4], bfr[8];
#pragma unroll
        for (int i = 0; i < 4; i++) af[i] = *(const bf16x8*)(cur + raOff[i]);
#pragma unroll
        for (int j = 0; j < 8; j++) bfr[j] = *(const bf16x8*)(cur + rbOff[j]);
#pragma unroll
        for (int i = 0; i < 4; i++)
#pragma unroll
            for (int j = 0; j < 8; j++)
                acc[i][j] = __builtin_amdgcn_mfma_f32_16x16x32_bf16(af[i], bfr[j], acc[i][j], 0, 0, 0);
        // ensure this wave's ds_reads of `cur` retired before anyone DMAs into it (next iter)
        asm volatile("s_waitcnt lgkmcnt(0)" ::: "memory");
        asm volatile("s_barrier" ::: "memory");
    }
}

// ---------------- fused q/k/v projection: z=0 K, z=1 V, z>=2 Q head z-2; bf16 y out ----------------
__global__ __launch_bounds__(256, 2) void k_gemm_proj_all(const ushort* __restrict__ tq,
                                                          const ushort* __restrict__ tk,
                                                          const ushort* __restrict__ tv,
                                                          const ushort* __restrict__ WqT,
                                                          const ushort* __restrict__ WkT,
                                                          const ushort* __restrict__ WvT,
                                                          const float* __restrict__ bq,
                                                          const float* __restrict__ bk,
                                                          const float* __restrict__ bv,
                                                          ushort* __restrict__ yq,
                                                          ushort* __restrict__ yk,
                                                          ushort* __restrict__ yv) {
    __shared__ ushort sh[GC_SH];
    int z = blockIdx.z;
    const ushort* A;
    const ushort* BT;
    const float* bias;
    ushort* C;
    int remap = 0, h = 0;
    if (z == 0) { A = tk; BT = WkT; bias = bk; C = yk; }
    else if (z == 1) { A = tv; BT = WvT; bias = bv; C = yv; }
    else {
        h = z - 2;
        A = tq; BT = WqT + (size_t)h * 512 * 512; bias = bq + (size_t)h * 512;
        C = yq; remap = 1;
    }
    f32x4 acc[4][8];
    int m0 = blockIdx.y * 256, n0 = blockIdx.x * 128;
    gemm_core256(A, BT, 512, 512, 512, m0, n0, sh, acc);
    int tid = threadIdx.x, w = tid >> 6, lane = tid & 63;
    int quad = lane >> 4, lx = lane & 15;
#pragma unroll
    for (int i = 0; i < 4; i++)
#pragma unroll
        for (int reg = 0; reg < 4; reg++) {
            int m = m0 + w * 64 + i * 16 + quad * 4 + reg;
            size_t orow = remap ? (size_t)((m >> 10) * H_ + h) * S_ + (m & 1023) : (size_t)m;
#pragma unroll
            for (int j = 0; j < 8; j++) {
                int n = n0 + j * 16 + lx;
                C[orow * 512 + n] = f2b(acc[i][j][reg] + bias[n]);
            }
        }
}

// ---------------- score GEMM (batched over z): dist -> E bf16, den atomic ----------------
// e = t^(-itau), t = 1+w+sqrt(w(w+2)), w = sq*min(2/(omq*okn), 2e6) clamped >=1e-7
// tau==1 fast path: e = rcp(t) exactly.
__global__ __launch_bounds__(256, 2) void k_gemm_score(const ushort* __restrict__ Aq,
                                                       const ushort* __restrict__ Bk,
                                                       ushort* __restrict__ E,
                                                       float* __restrict__ den,
                                                       const float* __restrict__ qn,
                                                       const float* __restrict__ kn,
                                                       const float* __restrict__ lamM1,
                                                       const float* __restrict__ stau) {
    __shared__ ushort sh[GC_SH];
    int b = blockIdx.z;
    Aq += (size_t)b * 8192 * 512;
    Bk += (size_t)b * 1024 * 512;
    E += (size_t)b * 8192 * 1024;
    den += (size_t)b * 8192;
    qn += (size_t)b * 8192;
    kn += (size_t)b * 1024;
    lamM1 += (size_t)b * 1024;
    f32x4 acc[4][8];
    int m0 = blockIdx.y * 256, n0 = blockIdx.x * 128;
    gemm_core256(Aq, Bk, 512, 512, 512, m0, n0, sh, acc);
    float itau = expf(stau[0]);
    bool tau1 = (itau == 1.0f);
    int tid = threadIdx.x, w_ = tid >> 6, lane = tid & 63;
    int quad = lane >> 4, lx = lane & 15;
    float knv[8], rk[8], lmv[8];
#pragma unroll
    for (int j = 0; j < 8; j++) {
        int n = n0 + j * 16 + lx;
        knv[j] = kn[n];
        rk[j] = __builtin_amdgcn_rcpf(1.0f - knv[j]);
        lmv[j] = lamM1[n];
    }
#pragma unroll
    for (int i = 0; i < 4; i++)
#pragma unroll
        for (int reg = 0; reg < 4; reg++) {
            int m = m0 + w_ * 64 + i * 16 + quad * 4 + reg;
            float q = qn[m];
            float rq2 = 2.0f * __builtin_amdgcn_rcpf(1.0f - q);
            float rsum = 0.0f;
#pragma unroll
            for (int j = 0; j < 8; j++) {
                float dot = acc[i][j][reg];
                float sq = fmaxf(q + knv[j] - 2.0f * dot, 0.0f);
                float rr2 = fminf(rq2 * rk[j], 2e6f);
                float w = fmaxf(sq * rr2, 1e-7f);
                float root = __builtin_amdgcn_sqrtf(__builtin_fmaf(w, w, 2.0f * w));
                float t = 1.0f + w + root;
                float e = tau1 ? __builtin_amdgcn_rcpf(t)
                               : __builtin_amdgcn_exp2f(-itau * __builtin_amdgcn_logf(t));
                ushort eb = f2b(e);
                int n = n0 + j * 16 + lx;
                E[(size_t)m * 1024 + n] = eb;
                rsum += b2f(eb) * lmv[j];
            }
            for (int o = 8; o; o >>= 1) rsum += __shfl_xor(rsum, o, 64);
            if (lx == 0) atomicAdd(&den[m], rsum);
        }
}

// ---------------- attn x V GEMM (batched over z): u = (E*lamV^T)/den -> bf16 U + atomic ss ----------------
__global__ __launch_bounds__(256, 2) void k_gemm_attnv(const ushort* __restrict__ E,
                                                       const ushort* __restrict__ VT,
                                                       const float* __restrict__ den,
                                                       ushort* __restrict__ Ub,
                                                       float* __restrict__ ssU) {
    __shared__ ushort sh[GC_SH];
    int b = blockIdx.z;
    E += (size_t)b * 8192 * 1024;
    VT += (size_t)b * 512 * 1024;
    den += (size_t)b * 8192;
    Ub += (size_t)b * 8192 * 512;
    ssU += (size_t)b * 8192;
    f32x4 acc[4][8];
    int m0 = blockIdx.y * 256, n0 = blockIdx.x * 128;
    gemm_core256(E, VT, 1024, 1024, 1024, m0, n0, sh, acc);
    int tid = threadIdx.x, w = tid >> 6, lane = tid & 63;
    int quad = lane >> 4, lx = lane & 15;
#pragma unroll
    for (int i = 0; i < 4; i++)
#pragma unroll
        for (int reg = 0; reg < 4; reg++) {
            int m = m0 + w * 64 + i * 16 + quad * 4 + reg;
            float inv = __builtin_amdgcn_rcpf(fmaxf(den[m], EPS_));
            float ssum = 0.0f;
#pragma unroll
            for (int j = 0; j < 8; j++) {
                int n = n0 + j * 16 + lx;
                float u = acc[i][j][reg] * inv;
                Ub[(size_t)m * 512 + n] = f2b(u);
                ssum += u * u;
            }
            for (int o = 8; o; o >>= 1) ssum += __shfl_xor(ssum, o, 64);
            if (lx == 0) atomicAdd(&ssU[m], ssum);
        }
}

// ---------------- output projection split-K over 8 head-chunks: Cp[z] = U_h @ Wo_h^T ----------------
__global__ __launch_bounds__(256, 2) void k_gemm_sk(const ushort* __restrict__ Ub,
                                                    const ushort* __restrict__ WoT,
                                                    float* __restrict__ Cp) {
    __shared__ ushort sh[GC_SH];
    int z = blockIdx.z;
    int m0 = blockIdx.y * 256, n0 = blockIdx.x * 128;
    int bb = m0 >> 10, s0 = m0 & 1023;
    const ushort* A = Ub + ((size_t)(bb * H_ + z) * S_ + s0) * 512;
    const ushort* BT = WoT + (size_t)z * 512;  // cols [z*512,+512) of k, ldb=4096
    float* C = Cp + (size_t)z * 4096 * 512;
    f32x4 acc[4][8];
    gemm_core256(A, BT, 512, 4096, 512, 0, n0, sh, acc);
    int tid = threadIdx.x, w = tid >> 6, lane = tid & 63;
    int quad = lane >> 4, lx = lane & 15;
#pragma unroll
    for (int i = 0; i < 4; i++)
#pragma unroll
        for (int reg = 0; reg < 4; reg++) {
            int m = m0 + w * 64 + i * 16 + quad * 4 + reg;
#pragma unroll
            for (int j = 0; j < 8; j++) {
                int n = n0 + j * 16 + lx;
                C[(size_t)m * 512 + n] = acc[i][j][reg];
            }
        }
}

// ---------------- hyper factors from row norms: Asc8[(b,s),h] ----------------
__global__ __launch_bounds__(256) void k_hyperfactors(const float* __restrict__ ssU,
                                                      float* __restrict__ Asc8) {
    int idx = blockIdx.x * 256 + threadIdx.x;
    if (idx >= B_ * S_) return;
    int b = idx >> 10, s = idx & 1023;
    float f12[8];
    float sum = 0.0f;
#pragma unroll
    for (int h = 0; h < H_; h++) {
        float ss = ssU[(size_t)(b * H_ + h) * S_ + s];
        float n = sqrtf(fmaxf(ss, EPS_));
        float a = 0.5f * atanhf(fminf(n, MAXT));
        float f1 = tanhf(a) / n;
        float mss = f1 * f1 * ss;
        float nm = sqrtf(fmaxf(mss, EPS_));
        float f2 = atanhf(fminf(nm, MAXT)) / nm;
        f12[h] = f1 * f2;
        sum += f12[h] * f12[h] * ss;
    }
    float nc = sqrtf(fmaxf(sum, EPS_));
    float f3 = tanhf(nc) / nc;
    float css = f3 * f3 * sum;
    float nc2 = sqrtf(fmaxf(css, EPS_));
    float f4 = atanhf(fminf(nc2, MAXT)) / nc2;
    float g = f3 * f4;
#pragma unroll
    for (int h = 0; h < H_; h++) Asc8[(size_t)idx * 8 + h] = f12[h] * g;
}

// ---------------- final reduce: out = expmap0(sum_z Asc8[r,z]*Cp[z][r,:] + bo) ----------------
__global__ __launch_bounds__(256) void k_final_reduce_expmap(const float* __restrict__ Cp,
                                                             const float* __restrict__ Asc8,
                                                             const float* __restrict__ bo,
                                                             float* __restrict__ out) {
    __shared__ float sm[8];
    int r = blockIdx.x;
    float a[8];
#pragma unroll
    for (int z = 0; z < 8; z++) a[z] = Asc8[(size_t)r * 8 + z];
    float v0 = bo[threadIdx.x], v1 = bo[threadIdx.x + 256];
#pragma unroll
    for (int z = 0; z < 8; z++) {
        const float* row = Cp + ((size_t)z * 4096 + r) * 512;
        v0 += a[z] * row[threadIdx.x];
        v1 += a[z] * row[threadIdx.x + 256];
    }
    float ss = blk_reduce_sum(v0 * v0 + v1 * v1, sm);
    float n = sqrtf(fmaxf(ss, EPS_));
    float f = tanhf(n) / n;
    float* o = out + (size_t)r * D_;
    o[threadIdx.x] = f * v0;
    o[threadIdx.x + 256] = f * v1;
}

// ---------------- logmap0 rows -> bf16 tangent (y selects q/k/v) ----------------
__global__ __launch_bounds__(256) void k_logmap_bf16(const float* __restrict__ q,
                                                     const float* __restrict__ k,
                                                     const float* __restrict__ v,
                                                     ushort* __restrict__ tq,
                                                     ushort* __restrict__ tk,
                                                     ushort* __restrict__ tv) {
    __shared__ float sm[8];
    const float* x = (blockIdx.y == 0) ? q : (blockIdx.y == 1) ? k : v;
    ushort* t = (blockIdx.y == 0) ? tq : (blockIdx.y == 1) ? tk : tv;
    int r = blockIdx.x;
    const float* xr = x + (size_t)r * D_;
    float v0 = xr[threadIdx.x], v1 = xr[threadIdx.x + 256];
    float ss = blk_reduce_sum(v0 * v0 + v1 * v1, sm);
    float n = sqrtf(fmaxf(ss, EPS_));
    float f = atanhf(fminf(n, MAXT)) / n;
    ushort* tr = t + (size_t)r * D_;
    tr[threadIdx.x] = f2b(f * v0);
    tr[threadIdx.x + 256] = f2b(f * v1);
}

// ---------------- expmap rows from bf16 y, with stats ----------------
// mode 1: bf16 ball + aux=clip(|ball|^2). mode 2: bf16 lam*ball + aux=lam-1.
__global__ __launch_bounds__(256) void k_expmap_stats(const ushort* __restrict__ y,
                                                      ushort* __restrict__ outb,
                                                      float* __restrict__ aux, int mode) {
    __shared__ float sm[8];
    int r = blockIdx.x;
    const ushort* yr = y + (size_t)r * D_;
    float v0 = b2f(yr[threadIdx.x]), v1 = b2f(yr[threadIdx.x + 256]);
    float ss = blk_reduce_sum(v0 * v0 + v1 * v1, sm);
    float n = sqrtf(fmaxf(ss, EPS_));
    float f = tanhf(n) / n;
    ushort h0 = f2b(f * v0), h1 = f2b(f * v1);
    float x0 = b2f(h0), x1 = b2f(h1);
    float ss2 = blk_reduce_sum(x0 * x0 + x1 * x1, sm);
    float bn2 = fminf(ss2, MAXT);
    ushort* o = outb + (size_t)r * D_;
    if (mode == 1) {
        o[threadIdx.x] = h0;
        o[threadIdx.x + 256] = h1;
        if (threadIdx.x == 0) aux[r] = bn2;
    } else {
        float lam = 2.0f / (1.0f - bn2);
        o[threadIdx.x] = f2b(lam * x0);
        o[threadIdx.x + 256] = f2b(lam * x1);
        if (threadIdx.x == 0) aux[r] = lam - 1.0f;
    }
}

// ---------------- transpose fp32 [R][C] -> bf16 [C][R] ----------------
__global__ __launch_bounds__(256) void k_transpose_f2b(const float* __restrict__ in,
                                                       ushort* __restrict__ out, int R, int C,
                                                       size_t zin, size_t zout) {
    __shared__ float t[32][33];
    in += (size_t)blockIdx.z * zin;
    out += (size_t)blockIdx.z * zout;
    int c0 = blockIdx.x * 32, r0 = blockIdx.y * 32;
    int tx = threadIdx.x & 31, ty = threadIdx.x >> 5;
    for (int rr = ty; rr < 32; rr += 8) t[rr][tx] = in[(size_t)(r0 + rr) * C + c0 + tx];
    __syncthreads();
    for (int rr = ty; rr < 32; rr += 8)
        out[(size_t)(c0 + rr) * R + r0 + tx] = f2b(t[tx][rr]);
}

// ---------------- transpose bf16 [R][C] -> bf16 [C][R] ----------------
__global__ __launch_bounds__(256) void k_transpose_b2b(const ushort* __restrict__ in,
                                                       ushort* __restrict__ out, int R, int C,
                                                       size_t zin, size_t zout) {
    __shared__ ushort t[32][34];
    in += (size_t)blockIdx.z * zin;
    out += (size_t)blockIdx.z * zout;
    int c0 = blockIdx.x * 32, r0 = blockIdx.y * 32;
    int tx = threadIdx.x & 31, ty = threadIdx.x >> 5;
    for (int rr = ty; rr < 32; rr += 8) t[rr][tx] = in[(size_t)(r0 + rr) * C + c0 + tx];
    __syncthreads();
    for (int rr = ty; rr < 32; rr += 8)
        out[(size_t)(c0 + rr) * R + r0 + tx] = t[tx][rr];
}

extern "C" void kernel_launch(void* const* d_in, const int* in_sizes, int n_in,
                              void* d_out, int out_size, void* d_ws, size_t ws_size,
                              hipStream_t stream) {
    (void)in_sizes; (void)n_in; (void)out_size; (void)ws_size;
    const float* query = (const float*)d_in[0];
    const float* key = (const float*)d_in[1];
    const float* value = (const float*)d_in[2];
    const float* Wq = (const float*)d_in[3];
    const float* bq = (const float*)d_in[4];
    const float* Wk = (const float*)d_in[5];
    const float* bk = (const float*)d_in[6];
    const float* Wv = (const float*)d_in[7];
    const float* bv = (const float*)d_in[8];
    const float* Wo = (const float*)d_in[9];
    const float* bo = (const float*)d_in[10];
    const float* stau = (const float*)d_in[11];
    float* out = (float*)d_out;

    char* p = (char*)d_ws;
    auto alloc = [&](size_t bytes) {
        char* r = p;
        p += (bytes + 255) & ~(size_t)255;
        return r;
    };
    ushort* tq = (ushort*)alloc((size_t)4096 * 512 * 2);
    ushort* tk = (ushort*)alloc((size_t)4096 * 512 * 2);
    ushort* tv = (ushort*)alloc((size_t)4096 * 512 * 2);
    ushort* WqT = (ushort*)alloc((size_t)8 * 512 * 512 * 2);
    ushort* WkT = (ushort*)alloc((size_t)512 * 512 * 2);
    ushort* WvT = (ushort*)alloc((size_t)512 * 512 * 2);
    ushort* WoT = (ushort*)alloc((size_t)4096 * 512 * 2);
    ushort* yq = (ushort*)alloc((size_t)32768 * 512 * 2);   // bf16 q tangent (pre-expmap)
    ushort* yk = (ushort*)alloc((size_t)4096 * 512 * 2);
    ushort* yv = (ushort*)alloc((size_t)4096 * 512 * 2);
    ushort* qh = (ushort*)alloc((size_t)32768 * 512 * 2);   // alias: Ub after score consumes qh
    ushort* kball = (ushort*)alloc((size_t)4096 * 512 * 2);
    ushort* lamv = (ushort*)alloc((size_t)4096 * 512 * 2);
    ushort* lamvT = (ushort*)alloc((size_t)4 * 512 * 1024 * 2);
    ushort* Sc = (ushort*)alloc((size_t)4 * 8192 * 1024 * 2);  // alias: Cp after attnv consumes E
    float* kn = (float*)alloc(4096 * 4);
    float* lamM1 = (float*)alloc(4096 * 4);
    float* qn = (float*)alloc(32768 * 4);
    float* den = (float*)alloc(32768 * 4);
    float* ssU = (float*)alloc(32768 * 4);  // adjacent to den: one memset covers both
    float* Asc8 = (float*)alloc(32768 * 4);
    ushort* Ub = qh;
    float* Cp = (float*)Sc;

    hipMemsetAsync(den, 0, 2 * 32768 * 4, stream);  // den + ssU

    // 1. tangent inputs (bf16)
    k_logmap_bf16<<<dim3(4096, 3), 256, 0, stream>>>(query, key, value, tq, tk, tv);

    // 2. weight transposes -> bf16 [N][K]
    k_transpose_f2b<<<dim3(16, 16, 1), 256, 0, stream>>>(Wk, WkT, 512, 512, 0, 0);
    k_transpose_f2b<<<dim3(16, 16, 1), 256, 0, stream>>>(Wv, WvT, 512, 512, 0, 0);
    k_transpose_f2b<<<dim3(16, 16, 8), 256, 0, stream>>>(Wq, WqT, 512, 512, (size_t)512 * 512,
                                                         (size_t)512 * 512);
    k_transpose_f2b<<<dim3(16, 128, 1), 256, 0, stream>>>(Wo, WoT, 4096, 512, 0, 0);

    // 3. all projections, one launch (z: 0=k,1=v,2..9=q heads), 256x128 dbuf tiles
    k_gemm_proj_all<<<dim3(4, 16, 10), 256, 0, stream>>>(tq, tk, tv, WqT, WkT, WvT, bq, bk, bv,
                                                         yq, yk, yv);

    // 4. expmap epilogues + stats (bf16 in/out)
    k_expmap_stats<<<4096, 256, 0, stream>>>(yk, kball, kn, 1);
    k_expmap_stats<<<4096, 256, 0, stream>>>(yv, lamv, lamM1, 2);
    k_expmap_stats<<<32768, 256, 0, stream>>>(yq, qh, qn, 1);
    k_transpose_b2b<<<dim3(16, 32, 4), 256, 0, stream>>>(lamv, lamvT, 1024, 512,
                                                         (size_t)1024 * 512, (size_t)512 * 1024);

    // 5. attention, batched over z
    k_gemm_score<<<dim3(8, 32, 4), 256, 0, stream>>>(qh, kball, Sc, den, qn, kn, lamM1, stau);
    k_gemm_attnv<<<dim3(4, 32, 4), 256, 0, stream>>>(Sc, lamvT, den, Ub, ssU);

    // 6. hyper factors (tiny)
    k_hyperfactors<<<16, 256, 0, stream>>>(ssU, Asc8);

    // 7. output projection split-K over 8 head-chunks + fused scaled-reduce/expmap
    k_gemm_sk<<<dim3(4, 16, 8), 256, 0, stream>>>(Ub, WoT, Cp);
    k_final_reduce_expmap<<<4096, 256, 0, stream>>>(Cp, Asc8, bo, out);
}

// Round 7
// 364.398 us; speedup vs baseline: 5.5641x; 1.0705x over previous
//
#include <hip/hip_runtime.h>
#include <math.h>

// Problem constants: B=4, S=1024, D=512, H=8
constexpr int B_ = 4, S_ = 1024, D_ = 512, H_ = 8;
constexpr float EPS_ = 1e-6f;
constexpr float MAXT = 1.0f - 1e-5f;

typedef __attribute__((ext_vector_type(8))) short bf16x8;
typedef __attribute__((ext_vector_type(4))) float f32x4;

__device__ __forceinline__ ushort f2b(float f) {
    unsigned u = __float_as_uint(f);
    unsigned r = u + 0x7fffu + ((u >> 16) & 1u);
    return (ushort)(r >> 16);
}
__device__ __forceinline__ float b2f(ushort h) {
    return __uint_as_float(((unsigned)h) << 16);
}

__device__ __forceinline__ void async16(const ushort* g, ushort* l) {
    __builtin_amdgcn_global_load_lds(
        (const __attribute__((address_space(1))) unsigned int*)g,
        (__attribute__((address_space(3))) unsigned int*)l, 16, 0, 0);
}

// ---------------- block reductions (blockDim.x == 256) ----------------
__device__ __forceinline__ float blk_reduce_sum(float v, float* sm) {
    for (int o = 32; o > 0; o >>= 1) v += __shfl_down(v, o, 64);
    int lane = threadIdx.x & 63, wid = threadIdx.x >> 6;
    if (lane == 0) sm[wid] = v;
    __syncthreads();
    if (threadIdx.x == 0) sm[0] = sm[0] + sm[1] + sm[2] + sm[3];
    __syncthreads();
    float r = sm[0];
    __syncthreads();
    return r;
}

// ---------------- MFMA NT-GEMM core 256x128, double-buffered K-loop ----------------
constexpr int GC_ABUF = 256 * 32;
constexpr int GC_BUF = (256 + 128) * 32;
constexpr int GC_SH = GC_BUF * 2;  // 48 KB

__device__ __forceinline__ void gemm_core256(const ushort* __restrict__ A,
                                             const ushort* __restrict__ B,
                                             int lda, int ldb, int K, int m0, int n0,
                                             ushort* __restrict__ sh, f32x4 acc[4][8]) {
    const int tid = threadIdx.x;
    const int w = tid >> 6, lane = tid & 63;
    const int quad = lane >> 4, lx = lane & 15;
    const int rr = lane >> 2, c = lane & 3;

    const ushort* aP[4];
    int aOff[4];
#pragma unroll
    for (int i = 0; i < 4; i++) {
        int r = w * 64 + i * 16 + rr;
        int q = c ^ ((r >> 1) & 3);
        aP[i] = A + (size_t)(m0 + r) * lda + q * 8;
        aOff[i] = (w * 64 + i * 16) * 32;
    }
    const ushort* bP[2];
    int bOff[2];
#pragma unroll
    for (int i = 0; i < 2; i++) {
        int r = w * 32 + i * 16 + rr;
        int q = c ^ ((r >> 1) & 3);
        bP[i] = B + (size_t)(n0 + r) * ldb + q * 8;
        bOff[i] = GC_ABUF + (w * 32 + i * 16) * 32;
    }

    int raOff[4], rbOff[8];
#pragma unroll
    for (int i = 0; i < 4; i++) {
        int ra = w * 64 + i * 16 + lx;
        raOff[i] = ra * 32 + (quad ^ ((ra >> 1) & 3)) * 8;
    }
#pragma unroll
    for (int j = 0; j < 8; j++) {
        int rb = j * 16 + lx;
        rbOff[j] = GC_ABUF + rb * 32 + (quad ^ ((rb >> 1) & 3)) * 8;
    }
#pragma unroll
    for (int i = 0; i < 4; i++)
#pragma unroll
        for (int j = 0; j < 8; j++) acc[i][j] = (f32x4)(0.0f);

#pragma unroll
    for (int i = 0; i < 4; i++) async16(aP[i], sh + aOff[i]);
#pragma unroll
    for (int i = 0; i < 2; i++) async16(bP[i], sh + bOff[i]);

    const int nsteps = K >> 5;
    for (int s = 0; s < nsteps; s++) {
        ushort* cur = sh + (s & 1) * GC_BUF;
        if (s + 1 < nsteps) {
            ushort* nxt = sh + ((s + 1) & 1) * GC_BUF;
            int k0 = (s + 1) << 5;
#pragma unroll
            for (int i = 0; i < 4; i++) async16(aP[i] + k0, nxt + aOff[i]);
#pragma unroll
            for (int i = 0; i < 2; i++) async16(bP[i] + k0, nxt + bOff[i]);
            asm volatile("s_waitcnt vmcnt(6)" ::: "memory");
        } else {
            asm volatile("s_waitcnt vmcnt(0)" ::: "memory");
        }
        asm volatile("s_barrier" ::: "memory");
        bf16x8 af[4], bfr[8];
#pragma unroll
        for (int i = 0; i < 4; i++) af[i] = *(const bf16x8*)(cur + raOff[i]);
#pragma unroll
        for (int j = 0; j < 8; j++) bfr[j] = *(const bf16x8*)(cur + rbOff[j]);
#pragma unroll
        for (int i = 0; i < 4; i++)
#pragma unroll
            for (int j = 0; j < 8; j++)
                acc[i][j] = __builtin_amdgcn_mfma_f32_16x16x32_bf16(af[i], bfr[j], acc[i][j], 0, 0, 0);
        asm volatile("s_waitcnt lgkmcnt(0)" ::: "memory");
        asm volatile("s_barrier" ::: "memory");
    }
}

// ---------------- fused q/k/v projection + per-row |y|^2 atomics ----------------
__global__ __launch_bounds__(256, 2) void k_gemm_proj_all(const ushort* __restrict__ tq,
                                                          const ushort* __restrict__ tk,
                                                          const ushort* __restrict__ tv,
                                                          const ushort* __restrict__ WqT,
                                                          const ushort* __restrict__ WkT,
                                                          const ushort* __restrict__ WvT,
                                                          const float* __restrict__ bq,
                                                          const float* __restrict__ bk,
                                                          const float* __restrict__ bv,
                                                          ushort* __restrict__ yq,
                                                          ushort* __restrict__ yk,
                                                          ushort* __restrict__ yv,
                                                          float* __restrict__ ssq,
                                                          float* __restrict__ ssk,
                                                          float* __restrict__ ssv) {
    __shared__ ushort sh[GC_SH];
    int z = blockIdx.z;
    const ushort* A;
    const ushort* BT;
    const float* bias;
    ushort* C;
    float* SS;
    int remap = 0, h = 0;
    if (z == 0) { A = tk; BT = WkT; bias = bk; C = yk; SS = ssk; }
    else if (z == 1) { A = tv; BT = WvT; bias = bv; C = yv; SS = ssv; }
    else {
        h = z - 2;
        A = tq; BT = WqT + (size_t)h * 512 * 512; bias = bq + (size_t)h * 512;
        C = yq; SS = ssq; remap = 1;
    }
    f32x4 acc[4][8];
    int m0 = blockIdx.y * 256, n0 = blockIdx.x * 128;
    gemm_core256(A, BT, 512, 512, 512, m0, n0, sh, acc);
    int tid = threadIdx.x, w = tid >> 6, lane = tid & 63;
    int quad = lane >> 4, lx = lane & 15;
#pragma unroll
    for (int i = 0; i < 4; i++)
#pragma unroll
        for (int reg = 0; reg < 4; reg++) {
            int m = m0 + w * 64 + i * 16 + quad * 4 + reg;
            size_t orow = remap ? (size_t)((m >> 10) * H_ + h) * S_ + (m & 1023) : (size_t)m;
            float ssum = 0.0f;
#pragma unroll
            for (int j = 0; j < 8; j++) {
                int n = n0 + j * 16 + lx;
                ushort hb = f2b(acc[i][j][reg] + bias[n]);
                C[orow * 512 + n] = hb;
                float yv_ = b2f(hb);
                ssum += yv_ * yv_;
            }
            for (int o = 8; o; o >>= 1) ssum += __shfl_xor(ssum, o, 64);
            if (lx == 0) atomicAdd(&SS[orow], ssum);
        }
}

// ---------------- ball factors from row norms ----------------
// rows [0,32768): q -> fq, qn2; [32768,36864): k -> fk, kn2; [36864,40960): v -> cv, dsc
__global__ __launch_bounds__(256) void k_ballfactors(const float* __restrict__ ssq,
                                                     const float* __restrict__ ssk,
                                                     const float* __restrict__ ssv,
                                                     float* __restrict__ fq,
                                                     float* __restrict__ qn2,
                                                     float* __restrict__ fk,
                                                     float* __restrict__ kn2,
                                                     float* __restrict__ cv,
                                                     float* __restrict__ dsc) {
    int idx = blockIdx.x * 256 + threadIdx.x;
    if (idx >= 40960) return;
    float ss;
    if (idx < 32768) ss = ssq[idx];
    else if (idx < 36864) ss = ssk[idx - 32768];
    else ss = ssv[idx - 36864];
    float n = sqrtf(fmaxf(ss, EPS_));
    float f = tanhf(n) / n;
    float bn2 = fminf(f * f * ss, MAXT);
    if (idx < 32768) {
        fq[idx] = f;
        qn2[idx] = bn2;
    } else if (idx < 36864) {
        fk[idx - 32768] = f;
        kn2[idx - 32768] = bn2;
    } else {
        int r = idx - 36864;
        float lam = 2.0f / (1.0f - bn2);
        float c = f * lam;
        cv[r] = c;
        dsc[r] = (lam - 1.0f) / c;
    }
}

// ---------------- score GEMM, XCD-swizzled: dist -> E' = e*cv bf16, den atomic ----------------
__global__ __launch_bounds__(256, 2) void k_gemm_score(const ushort* __restrict__ Yq,
                                                       const ushort* __restrict__ Yk,
                                                       ushort* __restrict__ E,
                                                       float* __restrict__ den,
                                                       const float* __restrict__ fq,
                                                       const float* __restrict__ qn2,
                                                       const float* __restrict__ fk,
                                                       const float* __restrict__ kn2,
                                                       const float* __restrict__ cv,
                                                       const float* __restrict__ dsc,
                                                       const float* __restrict__ stau) {
    __shared__ ushort sh[GC_SH];
    // XCD-aware swizzle: lin in [0,1024); each XCD owns 4 m-tiles x 8 n-tiles per batch
    int lin = blockIdx.x + 8 * blockIdx.y + 256 * blockIdx.z;
    int xcd = lin & 7, p = lin >> 3;
    int b = p >> 5, q_ = p & 31;
    int m0 = (4 * xcd + (q_ >> 3)) * 256;
    int n0 = (q_ & 7) * 128;
    const ushort* Aq = Yq + (size_t)b * 8192 * 512;
    const ushort* Bk = Yk + (size_t)b * 1024 * 512;
    E += (size_t)b * 8192 * 1024;
    den += (size_t)b * 8192;
    const float* fqb = fq + (size_t)b * 8192;
    const float* qn2b = qn2 + (size_t)b * 8192;
    const float* fkb = fk + (size_t)b * 1024;
    const float* kn2b = kn2 + (size_t)b * 1024;
    const float* cvb = cv + (size_t)b * 1024;
    const float* dscb = dsc + (size_t)b * 1024;

    f32x4 acc[4][8];
    gemm_core256(Aq, Bk, 512, 512, 512, m0, n0, sh, acc);
    float itau = expf(stau[0]);
    bool tau1 = (itau == 1.0f);
    int tid = threadIdx.x, w_ = tid >> 6, lane = tid & 63;
    int quad = lane >> 4, lx = lane & 15;
    float fkv[8], kn2v[8], cvv[8], dscv[8], rk[8];
#pragma unroll
    for (int j = 0; j < 8; j++) {
        int n = n0 + j * 16 + lx;
        fkv[j] = fkb[n];
        kn2v[j] = kn2b[n];
        rk[j] = __builtin_amdgcn_rcpf(1.0f - kn2v[j]);
        cvv[j] = cvb[n];
        dscv[j] = dscb[n];
    }
#pragma unroll
    for (int i = 0; i < 4; i++)
#pragma unroll
        for (int reg = 0; reg < 4; reg++) {
            int m = m0 + w_ * 64 + i * 16 + quad * 4 + reg;
            float fqm = fqb[m];
            float q = qn2b[m];
            float rq2 = 2.0f * __builtin_amdgcn_rcpf(1.0f - q);
            float rsum = 0.0f;
#pragma unroll
            for (int j = 0; j < 8; j++) {
                float dot = fqm * fkv[j] * acc[i][j][reg];
                float sq = fmaxf(q + kn2v[j] - 2.0f * dot, 0.0f);
                float rr2 = fminf(rq2 * rk[j], 2e6f);
                float w = fmaxf(sq * rr2, 1e-7f);
                float root = __builtin_amdgcn_sqrtf(__builtin_fmaf(w, w, 2.0f * w));
                float t = 1.0f + w + root;
                float e = tau1 ? __builtin_amdgcn_rcpf(t)
                               : __builtin_amdgcn_exp2f(-itau * __builtin_amdgcn_logf(t));
                ushort eb = f2b(e * cvv[j]);
                int n = n0 + j * 16 + lx;
                E[(size_t)m * 1024 + n] = eb;
                rsum += b2f(eb) * dscv[j];
            }
            for (int o = 8; o; o >>= 1) rsum += __shfl_xor(rsum, o, 64);
            if (lx == 0) atomicAdd(&den[m], rsum);
        }
}

// ---------------- attn x V GEMM, XCD-swizzled: u = (E' @ yv^T)/den -> bf16 U + atomic ss ----------------
__global__ __launch_bounds__(256, 2) void k_gemm_attnv(const ushort* __restrict__ E,
                                                       const ushort* __restrict__ VT,
                                                       const float* __restrict__ den,
                                                       ushort* __restrict__ Ub,
                                                       float* __restrict__ ssU) {
    __shared__ ushort sh[GC_SH];
    // lin in [0,512); each XCD owns 4 m-tiles x 4 n-tiles per batch
    int lin = blockIdx.x + 4 * blockIdx.y + 128 * blockIdx.z;
    int xcd = lin & 7, p = lin >> 3;
    int b = p >> 4, q_ = p & 15;
    int m0 = (4 * xcd + (q_ >> 2)) * 256;
    int n0 = (q_ & 3) * 128;
    E += (size_t)b * 8192 * 1024;
    VT += (size_t)b * 512 * 1024;
    den += (size_t)b * 8192;
    Ub += (size_t)b * 8192 * 512;
    ssU += (size_t)b * 8192;
    f32x4 acc[4][8];
    gemm_core256(E, VT, 1024, 1024, 1024, m0, n0, sh, acc);
    int tid = threadIdx.x, w = tid >> 6, lane = tid & 63;
    int quad = lane >> 4, lx = lane & 15;
#pragma unroll
    for (int i = 0; i < 4; i++)
#pragma unroll
        for (int reg = 0; reg < 4; reg++) {
            int m = m0 + w * 64 + i * 16 + quad * 4 + reg;
            float inv = __builtin_amdgcn_rcpf(fmaxf(den[m], EPS_));
            float ssum = 0.0f;
#pragma unroll
            for (int j = 0; j < 8; j++) {
                int n = n0 + j * 16 + lx;
                float u = acc[i][j][reg] * inv;
                Ub[(size_t)m * 512 + n] = f2b(u);
                ssum += u * u;
            }
            for (int o = 8; o; o >>= 1) ssum += __shfl_xor(ssum, o, 64);
            if (lx == 0) atomicAdd(&ssU[m], ssum);
        }
}

// ---------------- output projection split-K over 8 head-chunks ----------------
__global__ __launch_bounds__(256, 2) void k_gemm_sk(const ushort* __restrict__ Ub,
                                                    const ushort* __restrict__ WoT,
                                                    float* __restrict__ Cp) {
    __shared__ ushort sh[GC_SH];
    int z = blockIdx.z;
    int m0 = blockIdx.y * 256, n0 = blockIdx.x * 128;
    int bb = m0 >> 10, s0 = m0 & 1023;
    const ushort* A = Ub + ((size_t)(bb * H_ + z) * S_ + s0) * 512;
    const ushort* BT = WoT + (size_t)z * 512;
    float* C = Cp + (size_t)z * 4096 * 512;
    f32x4 acc[4][8];
    gemm_core256(A, BT, 512, 4096, 512, 0, n0, sh, acc);
    int tid = threadIdx.x, w = tid >> 6, lane = tid & 63;
    int quad = lane >> 4, lx = lane & 15;
#pragma unroll
    for (int i = 0; i < 4; i++)
#pragma unroll
        for (int reg = 0; reg < 4; reg++) {
            int m = m0 + w * 64 + i * 16 + quad * 4 + reg;
#pragma unroll
            for (int j = 0; j < 8; j++) {
                int n = n0 + j * 16 + lx;
                C[(size_t)m * 512 + n] = acc[i][j][reg];
            }
        }
}

// ---------------- hyper factors from |U|^2: Asc8[(b,s),h] ----------------
__global__ __launch_bounds__(256) void k_hyperfactors(const float* __restrict__ ssU,
                                                      float* __restrict__ Asc8) {
    int idx = blockIdx.x * 256 + threadIdx.x;
    if (idx >= B_ * S_) return;
    int b = idx >> 10, s = idx & 1023;
    float f12[8];
    float sum = 0.0f;
#pragma unroll
    for (int h = 0; h < H_; h++) {
        float ss = ssU[(size_t)(b * H_ + h) * S_ + s];
        float n = sqrtf(fmaxf(ss, EPS_));
        float a = 0.5f * atanhf(fminf(n, MAXT));
        float f1 = tanhf(a) / n;
        float mss = f1 * f1 * ss;
        float nm = sqrtf(fmaxf(mss, EPS_));
        float f2 = atanhf(fminf(nm, MAXT)) / nm;
        f12[h] = f1 * f2;
        sum += f12[h] * f12[h] * ss;
    }
    float nc = sqrtf(fmaxf(sum, EPS_));
    float f3 = tanhf(nc) / nc;
    float css = f3 * f3 * sum;
    float nc2 = sqrtf(fmaxf(css, EPS_));
    float f4 = atanhf(fminf(nc2, MAXT)) / nc2;
    float g = f3 * f4;
#pragma unroll
    for (int h = 0; h < H_; h++) Asc8[(size_t)idx * 8 + h] = f12[h] * g;
}

// ---------------- final reduce: out = expmap0(sum_z Asc8[r,z]*Cp[z][r,:] + bo) ----------------
__global__ __launch_bounds__(256) void k_final_reduce_expmap(const float* __restrict__ Cp,
                                                             const float* __restrict__ Asc8,
                                                             const float* __restrict__ bo,
                                                             float* __restrict__ out) {
    __shared__ float sm[8];
    int r = blockIdx.x;
    float a[8];
#pragma unroll
    for (int z = 0; z < 8; z++) a[z] = Asc8[(size_t)r * 8 + z];
    float v0 = bo[threadIdx.x], v1 = bo[threadIdx.x + 256];
#pragma unroll
    for (int z = 0; z < 8; z++) {
        const float* row = Cp + ((size_t)z * 4096 + r) * 512;
        v0 += a[z] * row[threadIdx.x];
        v1 += a[z] * row[threadIdx.x + 256];
    }
    float ss = blk_reduce_sum(v0 * v0 + v1 * v1, sm);
    float n = sqrtf(fmaxf(ss, EPS_));
    float f = tanhf(n) / n;
    float* o = out + (size_t)r * D_;
    o[threadIdx.x] = f * v0;
    o[threadIdx.x + 256] = f * v1;
}

// ---------------- logmap0 rows -> bf16 tangent ----------------
__global__ __launch_bounds__(256) void k_logmap_bf16(const float* __restrict__ q,
                                                     const float* __restrict__ k,
                                                     const float* __restrict__ v,
                                                     ushort* __restrict__ tq,
                                                     ushort* __restrict__ tk,
                                                     ushort* __restrict__ tv) {
    __shared__ float sm[8];
    const float* x = (blockIdx.y == 0) ? q : (blockIdx.y == 1) ? k : v;
    ushort* t = (blockIdx.y == 0) ? tq : (blockIdx.y == 1) ? tk : tv;
    int r = blockIdx.x;
    const float* xr = x + (size_t)r * D_;
    float v0 = xr[threadIdx.x], v1 = xr[threadIdx.x + 256];
    float ss = blk_reduce_sum(v0 * v0 + v1 * v1, sm);
    float n = sqrtf(fmaxf(ss, EPS_));
    float f = atanhf(fminf(n, MAXT)) / n;
    ushort* tr = t + (size_t)r * D_;
    tr[threadIdx.x] = f2b(f * v0);
    tr[threadIdx.x + 256] = f2b(f * v1);
}

// ---------------- square weight transposes (z: 0=Wk, 1=Wv, 2..9=Wq heads), fp32->bf16 ----------------
__global__ __launch_bounds__(256) void k_transpose_sqw(const float* __restrict__ Wk,
                                                       const float* __restrict__ Wv,
                                                       const float* __restrict__ Wq,
                                                       ushort* __restrict__ WkT,
                                                       ushort* __restrict__ WvT,
                                                       ushort* __restrict__ WqT) {
    __shared__ float t[32][33];
    int z = blockIdx.z;
    const float* in;
    ushort* out;
    if (z == 0) { in = Wk; out = WkT; }
    else if (z == 1) { in = Wv; out = WvT; }
    else { in = Wq + (size_t)(z - 2) * 512 * 512; out = WqT + (size_t)(z - 2) * 512 * 512; }
    int c0 = blockIdx.x * 32, r0 = blockIdx.y * 32;
    int tx = threadIdx.x & 31, ty = threadIdx.x >> 5;
    for (int rr = ty; rr < 32; rr += 8) t[rr][tx] = in[(size_t)(r0 + rr) * 512 + c0 + tx];
    __syncthreads();
    for (int rr = ty; rr < 32; rr += 8)
        out[(size_t)(c0 + rr) * 512 + r0 + tx] = f2b(t[tx][rr]);
}

// ---------------- transpose fp32 [R][C] -> bf16 [C][R] (Wo) ----------------
__global__ __launch_bounds__(256) void k_transpose_f2b(const float* __restrict__ in,
                                                       ushort* __restrict__ out, int R, int C) {
    __shared__ float t[32][33];
    int c0 = blockIdx.x * 32, r0 = blockIdx.y * 32;
    int tx = threadIdx.x & 31, ty = threadIdx.x >> 5;
    for (int rr = ty; rr < 32; rr += 8) t[rr][tx] = in[(size_t)(r0 + rr) * C + c0 + tx];
    __syncthreads();
    for (int rr = ty; rr < 32; rr += 8)
        out[(size_t)(c0 + rr) * R + r0 + tx] = f2b(t[tx][rr]);
}

// ---------------- transpose bf16 [R][C] -> bf16 [C][R] (yv per batch) ----------------
__global__ __launch_bounds__(256) void k_transpose_b2b(const ushort* __restrict__ in,
                                                       ushort* __restrict__ out, int R, int C,
                                                       size_t zin, size_t zout) {
    __shared__ ushort t[32][34];
    in += (size_t)blockIdx.z * zin;
    out += (size_t)blockIdx.z * zout;
    int c0 = blockIdx.x * 32, r0 = blockIdx.y * 32;
    int tx = threadIdx.x & 31, ty = threadIdx.x >> 5;
    for (int rr = ty; rr < 32; rr += 8) t[rr][tx] = in[(size_t)(r0 + rr) * C + c0 + tx];
    __syncthreads();
    for (int rr = ty; rr < 32; rr += 8)
        out[(size_t)(c0 + rr) * R + r0 + tx] = t[tx][rr];
}

extern "C" void kernel_launch(void* const* d_in, const int* in_sizes, int n_in,
                              void* d_out, int out_size, void* d_ws, size_t ws_size,
                              hipStream_t stream) {
    (void)in_sizes; (void)n_in; (void)out_size; (void)ws_size;
    const float* query = (const float*)d_in[0];
    const float* key = (const float*)d_in[1];
    const float* value = (const float*)d_in[2];
    const float* Wq = (const float*)d_in[3];
    const float* bq = (const float*)d_in[4];
    const float* Wk = (const float*)d_in[5];
    const float* bk = (const float*)d_in[6];
    const float* Wv = (const float*)d_in[7];
    const float* bv = (const float*)d_in[8];
    const float* Wo = (const float*)d_in[9];
    const float* bo = (const float*)d_in[10];
    const float* stau = (const float*)d_in[11];
    float* out = (float*)d_out;

    char* p = (char*)d_ws;
    auto alloc = [&](size_t bytes) {
        char* r = p;
        p += (bytes + 255) & ~(size_t)255;
        return r;
    };
    ushort* tq = (ushort*)alloc((size_t)4096 * 512 * 2);
    ushort* tk = (ushort*)alloc((size_t)4096 * 512 * 2);
    ushort* tv = (ushort*)alloc((size_t)4096 * 512 * 2);
    ushort* WqT = (ushort*)alloc((size_t)8 * 512 * 512 * 2);
    ushort* WkT = (ushort*)alloc((size_t)512 * 512 * 2);
    ushort* WvT = (ushort*)alloc((size_t)512 * 512 * 2);
    ushort* WoT = (ushort*)alloc((size_t)4096 * 512 * 2);
    ushort* yq = (ushort*)alloc((size_t)32768 * 512 * 2);
    ushort* yk = (ushort*)alloc((size_t)4096 * 512 * 2);
    ushort* yv = (ushort*)alloc((size_t)4096 * 512 * 2);
    ushort* yvT = (ushort*)alloc((size_t)4 * 512 * 1024 * 2);
    ushort* Ub = (ushort*)alloc((size_t)32768 * 512 * 2);
    ushort* Sc = (ushort*)alloc((size_t)4 * 8192 * 1024 * 2);  // alias: Cp after attnv consumes E
    // zero-init block (one memset): den, ssU, ssq, ssk, ssv
    float* den = (float*)alloc(32768 * 4);
    float* ssU = (float*)alloc(32768 * 4);
    float* ssq = (float*)alloc(32768 * 4);
    float* ssk = (float*)alloc(4096 * 4);
    float* ssv = (float*)alloc(4096 * 4);
    float* fq = (float*)alloc(32768 * 4);
    float* qn2 = (float*)alloc(32768 * 4);
    float* fk = (float*)alloc(4096 * 4);
    float* kn2 = (float*)alloc(4096 * 4);
    float* cv = (float*)alloc(4096 * 4);
    float* dsc = (float*)alloc(4096 * 4);
    float* Asc8 = (float*)alloc(32768 * 4);
    float* Cp = (float*)Sc;

    hipMemsetAsync(den, 0, (size_t)(32768 * 3 + 4096 * 2 + 192) * 4, stream);

    // 1. tangent inputs (bf16)
    k_logmap_bf16<<<dim3(4096, 3), 256, 0, stream>>>(query, key, value, tq, tk, tv);

    // 2. weight transposes -> bf16 [N][K]
    k_transpose_sqw<<<dim3(16, 16, 10), 256, 0, stream>>>(Wk, Wv, Wq, WkT, WvT, WqT);
    k_transpose_f2b<<<dim3(16, 128, 1), 256, 0, stream>>>(Wo, WoT, 4096, 512);

    // 3. all projections + per-row |y|^2 atomics
    k_gemm_proj_all<<<dim3(4, 16, 10), 256, 0, stream>>>(tq, tk, tv, WqT, WkT, WvT, bq, bk, bv,
                                                         yq, yk, yv, ssq, ssk, ssv);

    // 4. ball factors (replaces all expmap passes)
    k_ballfactors<<<160, 256, 0, stream>>>(ssq, ssk, ssv, fq, qn2, fk, kn2, cv, dsc);
    k_transpose_b2b<<<dim3(16, 32, 4), 256, 0, stream>>>(yv, yvT, 1024, 512,
                                                         (size_t)1024 * 512, (size_t)512 * 1024);

    // 5. attention (XCD-swizzled)
    k_gemm_score<<<dim3(8, 32, 4), 256, 0, stream>>>(yq, yk, Sc, den, fq, qn2, fk, kn2, cv, dsc,
                                                     stau);
    k_gemm_attnv<<<dim3(4, 32, 4), 256, 0, stream>>>(Sc, yvT, den, Ub, ssU);

    // 6. hyper factors (tiny)
    k_hyperfactors<<<16, 256, 0, stream>>>(ssU, Asc8);

    // 7. output projection split-K + fused scaled-reduce/expmap
    k_gemm_sk<<<dim3(4, 16, 8), 256, 0, stream>>>(Ub, WoT, Cp);
    k_final_reduce_expmap<<<4096, 256, 0, stream>>>(Cp, Asc8, bo, out);
}